// Round 14
// baseline (633.358 us; speedup 1.0000x reference)
//
#include <hip/hip_runtime.h>

typedef unsigned short u16;
typedef __attribute__((ext_vector_type(8))) short s16x8;   // 8 bf16 (4 VGPR)
typedef __attribute__((ext_vector_type(4))) float f32x4;
typedef __attribute__((ext_vector_type(8))) unsigned short u16x8;

__device__ __forceinline__ float b2f(u16 u) {
  union { unsigned int i; float f; } v; v.i = ((unsigned int)u) << 16; return v.f;
}
__device__ __forceinline__ u16 f2b(float f) {
  union { float f; unsigned int i; } v; v.f = f;
  unsigned int r = v.i + 0x7FFFu + ((v.i >> 16) & 1u);   // RNE
  return (u16)(r >> 16);
}
__device__ __forceinline__ int pk2(float a, float b) {
  return (int)f2b(a) | ((int)f2b(b) << 16);
}

// ---------------------------------------------------------------------------
// MFMA GEMM: C(bf16)[M,N] = A[M,K] @ W[K,N] + bias(f32). Wt = W^T bf16 [N][K].
// BM=BN=128, BK=64, 4 waves (2x2). A+W staged in LDS, XOR-swizzled.
// (r8/r12-verbatim — small grids need W in LDS; W-direct regressed in r13.)
// ---------------------------------------------------------------------------
template<bool RELU>
__global__ void __launch_bounds__(256) k_gemm(
    const u16* __restrict__ A, const u16* __restrict__ Wt,
    const float* __restrict__ bias, u16* __restrict__ C, int N, int K)
{
  __shared__ int4 smem4[2048];             // 32 KB
  char* AsB = (char*)smem4;
  char* WsB = (char*)smem4 + 16384;
  const int t = threadIdx.x;
  const int lane = t & 63, wid = t >> 6;
  const int wm = wid >> 1, wn = wid & 1;
  const int l16 = lane & 15, lhi = lane >> 4;
  const int bCol = blockIdx.x * 128;
  const int bRow = blockIdx.y * 128;

  f32x4 acc[4][4];
#pragma unroll
  for (int i = 0; i < 4; ++i)
#pragma unroll
    for (int j = 0; j < 4; ++j) acc[i][j] = (f32x4){0.f, 0.f, 0.f, 0.f};

  const int nk = K >> 6;
  for (int kt = 0; kt < nk; ++kt) {
    const int k0 = kt << 6;
    int4 av[4], wv[4];
#pragma unroll
    for (int i = 0; i < 4; ++i) {
      int L = i * 4096 + t * 16;
      int r = L >> 7, cl = (L >> 4) & 7;
      av[i] = *(const int4*)(A + (size_t)(bRow + r) * K + k0 + cl * 8);
      wv[i] = *(const int4*)(Wt + (size_t)(bCol + r) * K + k0 + cl * 8);
    }
    if (kt) __syncthreads();
#pragma unroll
    for (int i = 0; i < 4; ++i) {
      int L = i * 4096 + t * 16;
      int r = L >> 7, cl = (L >> 4) & 7;
      int off = r * 128 + ((cl ^ (r & 7)) << 4);
      *(int4*)(AsB + off) = av[i];
      *(int4*)(WsB + off) = wv[i];
    }
    __syncthreads();
#pragma unroll
    for (int kk = 0; kk < 2; ++kk) {
      s16x8 af[4], bfr[4];
#pragma unroll
      for (int mt = 0; mt < 4; ++mt) {
        int r = wm * 64 + mt * 16 + l16;
        int ch = kk * 4 + lhi;
        af[mt] = *(const s16x8*)(AsB + r * 128 + ((ch ^ (r & 7)) << 4));
      }
#pragma unroll
      for (int nt = 0; nt < 4; ++nt) {
        int r = wn * 64 + nt * 16 + l16;
        int ch = kk * 4 + lhi;
        bfr[nt] = *(const s16x8*)(WsB + r * 128 + ((ch ^ (r & 7)) << 4));
      }
#pragma unroll
      for (int mt = 0; mt < 4; ++mt)
#pragma unroll
        for (int nt = 0; nt < 4; ++nt)
          acc[mt][nt] = __builtin_amdgcn_mfma_f32_16x16x32_bf16(
              af[mt], bfr[nt], acc[mt][nt], 0, 0, 0);
    }
  }
#pragma unroll
  for (int mt = 0; mt < 4; ++mt) {
#pragma unroll
    for (int nt = 0; nt < 4; ++nt) {
      int cg = bCol + wn * 64 + nt * 16 + l16;
      float bv = bias[cg];
#pragma unroll
      for (int rg = 0; rg < 4; ++rg) {
        int rgl = bRow + wm * 64 + mt * 16 + lhi * 4 + rg;
        float v = acc[mt][nt][rg] + bv;
        if (RELU) v = fmaxf(v, 0.f);
        C[(size_t)rgl * N + cg] = f2b(v);
      }
    }
  }
}

// ---------------------------------------------------------------------------
// Fused keys projections: [KV | QB](bf16) = keys(f32)[M,256] @ W[256,384].
// BM=128, BN=384 single pass, 512 threads = 8 waves (2x4).
// BARRIER-FREE main loop: A fragments loaded DIRECT from row-major f32 keys
// (one aligned 32B slice per lane, packed in-reg); W fragments direct from
// L2. No LDS until the epilogue C-bounce -> waves fully independent.
// A re-read 4x by wn-groups (L1/L2 temporal hits); keys L3-resident.
// ---------------------------------------------------------------------------
__global__ void __launch_bounds__(512, 2) k_gemm_kvq(
    const float* __restrict__ A, const u16* __restrict__ Wt,
    const float* __restrict__ bias, u16* __restrict__ KV, u16* __restrict__ QB)
{
  __shared__ char smem[49152];             // epilogue ldsO only
  const int t = threadIdx.x;
  const int lane = t & 63, wid = t >> 6;
  const int wm = wid >> 2, wn = wid & 3;   // 2 x 4 waves
  const int l16 = lane & 15, lhi = lane >> 4;
  const int bRow = blockIdx.x * 128;

  f32x4 acc[4][6];
#pragma unroll
  for (int i = 0; i < 4; ++i)
#pragma unroll
    for (int j = 0; j < 6; ++j) acc[i][j] = (f32x4){0.f, 0.f, 0.f, 0.f};

#pragma unroll
  for (int kks = 0; kks < 8; ++kks) {      // 8 k-slices of 32
    const int ko = kks * 32 + lhi * 8;
    s16x8 af[4], bfr[6];
#pragma unroll
    for (int mt = 0; mt < 4; ++mt) {       // A direct: 8 f32 -> 8 bf16
      int row = bRow + wm * 64 + mt * 16 + l16;
      const float* ap = A + (size_t)row * 256 + ko;
      float4 x = *(const float4*)ap;
      float4 y = *(const float4*)(ap + 4);
      int4 p = (int4){pk2(x.x, x.y), pk2(x.z, x.w),
                      pk2(y.x, y.y), pk2(y.z, y.w)};
      af[mt] = *(s16x8*)&p;
    }
#pragma unroll
    for (int nt = 0; nt < 6; ++nt) {       // W direct from L2
      int row = wn * 96 + nt * 16 + l16;
      bfr[nt] = *(const s16x8*)(Wt + (size_t)row * 256 + ko);
    }
#pragma unroll
    for (int mt = 0; mt < 4; ++mt)
#pragma unroll
      for (int nt = 0; nt < 6; ++nt)
        acc[mt][nt] = __builtin_amdgcn_mfma_f32_16x16x32_bf16(
            af[mt], bfr[nt], acc[mt][nt], 0, 0, 0);
  }
  // epilogue: two 64-row halves bounced through LDS, coalesced int4 out
  u16* ldsO = (u16*)smem;                  // [64][384] u16 = 48KB
  for (int half = 0; half < 2; ++half) {
    __syncthreads();
    if (wm == half) {
#pragma unroll
      for (int mt = 0; mt < 4; ++mt) {
#pragma unroll
        for (int nt = 0; nt < 6; ++nt) {
          int cg = wn * 96 + nt * 16 + l16;
          float bv = bias[cg];
#pragma unroll
          for (int rg = 0; rg < 4; ++rg) {
            int r = mt * 16 + lhi * 4 + rg;
            ldsO[r * 384 + cg] = f2b(acc[mt][nt][rg] + bv);
          }
        }
      }
    }
    __syncthreads();
#pragma unroll
    for (int i = 0; i < 6; ++i) {
      int chunk = i * 512 + t;             // 64 rows x 48 16B-chunks
      int r = chunk / 48, c8 = chunk - r * 48;
      int row = bRow + half * 64 + r;
      int4 v = *(int4*)(ldsO + r * 384 + c8 * 8);
      if (c8 < 32) *(int4*)(KV + (size_t)row * 256 + c8 * 8) = v;
      else         *(int4*)(QB + (size_t)row * 128 + (c8 - 32) * 8) = v;
    }
  }
}

// ---------------------------------------------------------------------------
// i2t out-proj + residual + LN4: out(f32)[M][256] =
// LN( A[M,128](bf16) @ W[128,256] + bias + res(f32) ) * g + b.
// BM=64, BN=256, 4 waves 2x2. W direct from L2 (grid 2048 -> TLP hides it);
// A in LDS (8 KB). grid = M/64. (r12-verbatim.)
// ---------------------------------------------------------------------------
__global__ void __launch_bounds__(256) k_gemm_ln(
    const u16* __restrict__ A, const u16* __restrict__ Wt,
    const float* __restrict__ bias, const float* __restrict__ res,
    const float* __restrict__ g, const float* __restrict__ bl,
    float* __restrict__ out)
{
  __shared__ int4 smem4[512];              // 8 KB A-tile
  __shared__ float rsum[2][32][2], rsq[2][32][2];
  char* AsB = (char*)smem4;
  const int t = threadIdx.x;
  const int lane = t & 63, wid = t >> 6;
  const int wm = wid >> 1, wn = wid & 1;
  const int l16 = lane & 15, lhi = lane >> 4;
  const int bRow = blockIdx.x * 64;

  f32x4 acc[2][8];
#pragma unroll
  for (int i = 0; i < 2; ++i)
#pragma unroll
    for (int j = 0; j < 8; ++j) acc[i][j] = (f32x4){0.f, 0.f, 0.f, 0.f};

  for (int kt = 0; kt < 2; ++kt) {
    const int k0 = kt << 6;
    int4 av[2];
#pragma unroll
    for (int i = 0; i < 2; ++i) {          // A: 64 x 64
      int L = i * 4096 + t * 16;
      int r = L >> 7, cl = (L >> 4) & 7;
      av[i] = *(const int4*)(A + (size_t)(bRow + r) * 128 + k0 + cl * 8);
    }
    if (kt) __syncthreads();
#pragma unroll
    for (int i = 0; i < 2; ++i) {
      int L = i * 4096 + t * 16;
      int r = L >> 7, cl = (L >> 4) & 7;
      *(int4*)(AsB + r * 128 + ((cl ^ (r & 7)) << 4)) = av[i];
    }
    __syncthreads();
#pragma unroll
    for (int kk = 0; kk < 2; ++kk) {
      s16x8 af[2], bfr[8];
#pragma unroll
      for (int nt = 0; nt < 8; ++nt) {     // W fragments direct from L2
        int row = wn * 128 + nt * 16 + l16;
        bfr[nt] = *(const s16x8*)(Wt + (size_t)row * 128 + k0 + kk * 32 + lhi * 8);
      }
#pragma unroll
      for (int mt = 0; mt < 2; ++mt) {
        int r = wm * 32 + mt * 16 + l16;
        int ch = kk * 4 + lhi;
        af[mt] = *(const s16x8*)(AsB + r * 128 + ((ch ^ (r & 7)) << 4));
      }
#pragma unroll
      for (int mt = 0; mt < 2; ++mt)
#pragma unroll
        for (int nt = 0; nt < 8; ++nt)
          acc[mt][nt] = __builtin_amdgcn_mfma_f32_16x16x32_bf16(
              af[mt], bfr[nt], acc[mt][nt], 0, 0, 0);
    }
  }
#pragma unroll
  for (int mt = 0; mt < 2; ++mt) {
#pragma unroll
    for (int nt = 0; nt < 8; ++nt) {
      int cg = wn * 128 + nt * 16 + l16;
      float bv = bias[cg];
#pragma unroll
      for (int rg = 0; rg < 4; ++rg) {
        int row = bRow + wm * 32 + mt * 16 + lhi * 4 + rg;
        acc[mt][nt][rg] += bv + res[(size_t)row * 256 + cg];
      }
    }
  }
#pragma unroll
  for (int mt = 0; mt < 2; ++mt) {
#pragma unroll
    for (int rg = 0; rg < 4; ++rg) {
      float ps = 0.f, pq = 0.f;
#pragma unroll
      for (int nt = 0; nt < 8; ++nt) {
        float v = acc[mt][nt][rg];
        ps += v; pq += v * v;
      }
#pragma unroll
      for (int msk = 1; msk < 16; msk <<= 1) {
        ps += __shfl_xor(ps, msk);
        pq += __shfl_xor(pq, msk);
      }
      if (l16 == 0) {
        int rl = mt * 16 + lhi * 4 + rg;
        rsum[wm][rl][wn] = ps;
        rsq[wm][rl][wn] = pq;
      }
    }
  }
  __syncthreads();
#pragma unroll
  for (int mt = 0; mt < 2; ++mt) {
#pragma unroll
    for (int rg = 0; rg < 4; ++rg) {
      int rl = mt * 16 + lhi * 4 + rg;
      float ts = rsum[wm][rl][0] + rsum[wm][rl][1];
      float tq = rsq[wm][rl][0] + rsq[wm][rl][1];
      float mean = ts * (1.f / 256.f);
      float var = tq * (1.f / 256.f) - mean * mean;
      float rstd = rsqrtf(var + 1e-5f);
      int row = bRow + wm * 32 + rl;
#pragma unroll
      for (int nt = 0; nt < 8; ++nt) {
        int cg = wn * 128 + nt * 16 + l16;
        out[(size_t)row * 256 + cg] =
            (acc[mt][nt][rg] - mean) * rstd * g[cg] + bl[cg];
      }
    }
  }
}

// ---------------------------------------------------------------------------
// weight prep. mode 0: transpose f32[K,N] -> bf16 dst[n*K+k]. mode 1: f32 copy.
// ---------------------------------------------------------------------------
struct TDesc { const float* src; void* dst; int K; int N; int mode; int blk0; };
struct TArgs { TDesc d[24]; int n; };

__global__ void __launch_bounds__(256) k_trans(TArgs a)
{
  int blk = blockIdx.x;
  int i = 0;
  while (i + 1 < a.n && blk >= a.d[i + 1].blk0) ++i;
  TDesc td = a.d[i];
  int e = (blk - td.blk0) * 256 + threadIdx.x;
  int tot = td.K * td.N;
  if (e >= tot) return;
  if (td.mode == 0) {
    int k = e / td.N, n = e - k * td.N;
    ((u16*)td.dst)[(size_t)n * td.K + k] = f2b(td.src[e]);
  } else {
    ((float*)td.dst)[e] = td.src[e];
  }
}

// ---------------------------------------------------------------------------
__global__ void __launch_bounds__(256) k_addpe(
    const float* __restrict__ q, const float* __restrict__ pe,
    float* __restrict__ outf, u16* __restrict__ outb)
{
  int i = blockIdx.x * 256 + threadIdx.x;
  float v = q[i] + pe[i];
  outf[i] = v;
  outb[i] = f2b(v);
}

// ---------------------------------------------------------------------------
// self-attention: per (b,h) block of 64 threads. QKV packed bf16 [1024,768].
// ---------------------------------------------------------------------------
__global__ void __launch_bounds__(64) k_attn_sa(
    const u16* __restrict__ QKV, u16* __restrict__ out)
{
  __shared__ float Q[32][33], K[32][33], V[32][33];
  int b = blockIdx.x >> 3, h = blockIdx.x & 7;
  int t = threadIdx.x;
  for (int idx = t; idx < 1024; idx += 64) {
    int i = idx >> 5, d = idx & 31;
    size_t base = (size_t)(b * 32 + i) * 768 + h * 32 + d;
    Q[i][d] = b2f(QKV[base]);
    K[i][d] = b2f(QKV[base + 256]);
    V[i][d] = b2f(QKV[base + 512]);
  }
  __syncthreads();
  int i = t & 31, half = t >> 5;
  float s[16];
#pragma unroll
  for (int jj = 0; jj < 16; ++jj) {
    int j = half * 16 + jj;
    float a = 0.f;
#pragma unroll
    for (int d = 0; d < 32; ++d) a += Q[i][d] * K[j][d];
    s[jj] = a * 0.17677669529663687f;
  }
  float m = s[0];
#pragma unroll
  for (int jj = 1; jj < 16; ++jj) m = fmaxf(m, s[jj]);
  m = fmaxf(m, __shfl_xor(m, 32));
  float sum = 0.f;
#pragma unroll
  for (int jj = 0; jj < 16; ++jj) { s[jj] = __expf(s[jj] - m); sum += s[jj]; }
  sum += __shfl_xor(sum, 32);
  float o[32];
#pragma unroll
  for (int d = 0; d < 32; ++d) o[d] = 0.f;
#pragma unroll
  for (int jj = 0; jj < 16; ++jj) {
    int j = half * 16 + jj;
    float p = s[jj];
#pragma unroll
    for (int d = 0; d < 32; ++d) o[d] += p * V[j][d];
  }
  float inv = 1.f / sum;
#pragma unroll
  for (int d = 0; d < 32; ++d) {
    float v = o[d] + __shfl_xor(o[d], 32);
    if (half == 0) out[(size_t)(b * 32 + i) * 256 + h * 32 + d] = f2b(v * inv);
  }
}

// ---------------------------------------------------------------------------
// t2i partial attention (split-K flash). Grid (32 chunks, 32 b), 128 threads.
// ---------------------------------------------------------------------------
__global__ void __launch_bounds__(128) k_attn_t2i_part(
    const u16* __restrict__ Qt, const u16* __restrict__ KV,
    float* __restrict__ part)
{
  __shared__ int4 kvs[4096];               // 64 KB = 128 rows x 256 u16
  int c = blockIdx.x, b = blockIdx.y;
  int tid = threadIdx.x;
  const int4* src = (const int4*)(KV + ((size_t)b * 4096 + c * 128) * 256);
  for (int i = tid; i < 4096; i += 128) kvs[i] = src[i];
  __syncthreads();
  int qp = tid >> 3, h = tid & 7;
  const u16* lds = (const u16*)kvs;

  float q0[16], q1[16];
  {
    const u16* p0 = Qt + (size_t)(b * 32 + qp) * 128 + h * 16;
    const u16* p1 = Qt + (size_t)(b * 32 + qp + 16) * 128 + h * 16;
    u16x8 a0 = *(const u16x8*)p0, b0 = *(const u16x8*)(p0 + 8);
    u16x8 a1 = *(const u16x8*)p1, b1 = *(const u16x8*)(p1 + 8);
#pragma unroll
    for (int e = 0; e < 8; ++e) {
      q0[e] = b2f(a0[e]); q0[8 + e] = b2f(b0[e]);
      q1[e] = b2f(a1[e]); q1[8 + e] = b2f(b1[e]);
    }
  }
  float m0 = -INFINITY, s0 = 0.f, m1 = -INFINITY, s1 = 0.f;
  float acc0[16], acc1[16];
#pragma unroll
  for (int d = 0; d < 16; ++d) { acc0[d] = 0.f; acc1[d] = 0.f; }

  for (int j = 0; j < 128; ++j) {
    const u16* kr = lds + j * 256 + h * 16;
    u16x8 ka = *(const u16x8*)kr;
    u16x8 kb = *(const u16x8*)(kr + 8);
    float l0 = 0.f, l1 = 0.f;
#pragma unroll
    for (int e = 0; e < 8; ++e) {
      float klo = b2f(ka[e]), khi = b2f(kb[e]);
      l0 += q0[e] * klo + q0[8 + e] * khi;
      l1 += q1[e] * klo + q1[8 + e] * khi;
    }
    l0 *= 0.25f; l1 *= 0.25f;
    const u16* vr = kr + 128;
    u16x8 va = *(const u16x8*)vr;
    u16x8 vb = *(const u16x8*)(vr + 8);
    float nm0 = fmaxf(m0, l0), nm1 = fmaxf(m1, l1);
    float c0 = __expf(m0 - nm0), p0 = __expf(l0 - nm0);
    float c1 = __expf(m1 - nm1), p1 = __expf(l1 - nm1);
    s0 = s0 * c0 + p0; s1 = s1 * c1 + p1;
#pragma unroll
    for (int e = 0; e < 8; ++e) {
      float vlo = b2f(va[e]), vhi = b2f(vb[e]);
      acc0[e] = acc0[e] * c0 + p0 * vlo;
      acc0[8 + e] = acc0[8 + e] * c0 + p0 * vhi;
      acc1[e] = acc1[e] * c1 + p1 * vlo;
      acc1[8 + e] = acc1[8 + e] * c1 + p1 * vhi;
    }
    m0 = nm0; m1 = nm1;
  }
  float* r0 = part + (((size_t)(b * 32 + qp) * 8 + h) * 32 + c) * 18;
  float* r1 = part + (((size_t)(b * 32 + qp + 16) * 8 + h) * 32 + c) * 18;
#pragma unroll
  for (int d = 0; d < 16; ++d) { r0[d] = acc0[d]; r1[d] = acc1[d]; }
  r0[16] = m0; r0[17] = s0;
  r1[16] = m1; r1[17] = s1;
}

// ---------------------------------------------------------------------------
// t2i merge: block (b,h); thread merges 32 chunk partials for 2 dims.
// ---------------------------------------------------------------------------
__global__ void __launch_bounds__(256) k_attn_t2i_merge(
    const float* __restrict__ part, u16* __restrict__ out)
{
  int b = blockIdx.x >> 3, h = blockIdx.x & 7;
  int q = threadIdx.x >> 3, ds = threadIdx.x & 7;
  const float* base = part + (((size_t)(b * 32 + q) * 8 + h) * 32) * 18;
  float mg = -INFINITY;
#pragma unroll 4
  for (int c = 0; c < 32; ++c) mg = fmaxf(mg, base[c * 18 + 16]);
  float sg = 0.f, a0 = 0.f, a1 = 0.f;
#pragma unroll 4
  for (int c = 0; c < 32; ++c) {
    const float* rec = base + c * 18;
    float w = __expf(rec[16] - mg);
    sg += rec[17] * w;
    a0 += rec[ds * 2] * w;
    a1 += rec[ds * 2 + 1] * w;
  }
  float inv = 1.f / sg;
  u16* op = out + (size_t)(b * 32 + q) * 128 + h * 16 + ds * 2;
  op[0] = f2b(a0 * inv);
  op[1] = f2b(a1 * inv);
}

// ---------------------------------------------------------------------------
// i2t cross-attn: each key row attends over 32 queries, d=16, scale=0.25.
// ---------------------------------------------------------------------------
__global__ void __launch_bounds__(256) k_attn_i2t(
    const u16* __restrict__ Qb, const u16* __restrict__ Kc,
    const u16* __restrict__ Vc, u16* __restrict__ out)
{
  __shared__ float Kl[32][132], Vl[32][132];
  int blk = blockIdx.x;
  int b = blk >> 7;
  int r0 = (blk & 127) * 32;
  for (int idx = threadIdx.x; idx < 4096; idx += 256) {
    int j = idx >> 7, c = idx & 127;
    Kl[j][c] = b2f(Kc[(size_t)(b * 32 + j) * 128 + c]);
    Vl[j][c] = b2f(Vc[(size_t)(b * 32 + j) * 128 + c]);
  }
  __syncthreads();
  int lr = threadIdx.x >> 3, h = threadIdx.x & 7;
  size_t row = (size_t)b * 4096 + r0 + lr;
  const u16* qp = Qb + row * 128 + h * 16;
  float q[16];
  {
    u16x8 qa = *(const u16x8*)qp;
    u16x8 qb2 = *(const u16x8*)(qp + 8);
#pragma unroll
    for (int e = 0; e < 8; ++e) { q[e] = b2f(qa[e]); q[8 + e] = b2f(qb2[e]); }
  }
  float lg[32];
  float mx = -INFINITY;
#pragma unroll
  for (int j = 0; j < 32; ++j) {
    float a = 0.f;
#pragma unroll
    for (int d = 0; d < 16; ++d) a += q[d] * Kl[j][h * 16 + d];
    lg[j] = a * 0.25f;
    mx = fmaxf(mx, lg[j]);
  }
  float sum = 0.f;
#pragma unroll
  for (int j = 0; j < 32; ++j) { lg[j] = __expf(lg[j] - mx); sum += lg[j]; }
  float acc[16];
#pragma unroll
  for (int d = 0; d < 16; ++d) acc[d] = 0.f;
#pragma unroll
  for (int j = 0; j < 32; ++j) {
    float p = lg[j];
#pragma unroll
    for (int d = 0; d < 16; ++d) acc[d] += p * Vl[j][h * 16 + d];
  }
  float inv = 1.f / sum;
  u16* op = out + row * 128 + h * 16;
#pragma unroll
  for (int d = 0; d < 16; ++d) op[d] = f2b(acc[d] * inv);
}

// ---------------------------------------------------------------------------
// y = LN(res_f32 + delta_bf16); g/b/pe f32. Optional f32 / bf16 / (y+pe) outs.
// ---------------------------------------------------------------------------
__global__ void __launch_bounds__(256) k_addln_small(
    const float* __restrict__ res, const u16* __restrict__ delta,
    const float* __restrict__ g, const float* __restrict__ bb,
    float* outf, u16* outb, const float* pe, u16* outpe)
{
  int row = blockIdx.x * 4 + (threadIdx.x >> 6);
  int lane = threadIdx.x & 63;
  size_t base = (size_t)row * 256 + lane * 4;
  float4 xv = *(const float4*)(res + base);
  ushort4 dv = *(const ushort4*)(delta + base);
  float v0 = xv.x + b2f(dv.x), v1 = xv.y + b2f(dv.y);
  float v2 = xv.z + b2f(dv.z), v3 = xv.w + b2f(dv.w);
  float sum = v0 + v1 + v2 + v3;
  float sq = v0 * v0 + v1 * v1 + v2 * v2 + v3 * v3;
#pragma unroll
  for (int msk = 1; msk < 64; msk <<= 1) {
    sum += __shfl_xor(sum, msk);
    sq += __shfl_xor(sq, msk);
  }
  float mean = sum * (1.f / 256.f);
  float var = sq * (1.f / 256.f) - mean * mean;
  float rstd = rsqrtf(var + 1e-5f);
  float4 gv = *(const float4*)(g + lane * 4);
  float4 bv = *(const float4*)(bb + lane * 4);
  float y0 = (v0 - mean) * rstd * gv.x + bv.x;
  float y1 = (v1 - mean) * rstd * gv.y + bv.y;
  float y2 = (v2 - mean) * rstd * gv.z + bv.z;
  float y3 = (v3 - mean) * rstd * gv.w + bv.w;
  if (outf) { float4 o{y0, y1, y2, y3}; *(float4*)(outf + base) = o; }
  if (outb) {
    ushort4 o{f2b(y0), f2b(y1), f2b(y2), f2b(y3)};
    *(ushort4*)(outb + base) = o;
  }
  if (outpe) {
    float4 pv = *(const float4*)(pe + base);
    ushort4 o{f2b(y0 + pv.x), f2b(y1 + pv.y), f2b(y2 + pv.z), f2b(y3 + pv.w)};
    *(ushort4*)(outpe + base) = o;
  }
}

// ---------------------------------------------------------------------------
extern "C" void kernel_launch(void* const* d_in, const int* in_sizes, int n_in,
                              void* d_out, int out_size, void* d_ws, size_t ws_size,
                              hipStream_t stream)
{
  (void)in_sizes; (void)n_in; (void)out_size; (void)ws_size;
  const float* queries = (const float*)d_in[0];
  const float* keys    = (const float*)d_in[1];
  const float* qpe     = (const float*)d_in[2];
  const float* sa_qw = (const float*)d_in[3];  const float* sa_qb = (const float*)d_in[4];
  const float* sa_kw = (const float*)d_in[5];  const float* sa_kb = (const float*)d_in[6];
  const float* sa_vw = (const float*)d_in[7];  const float* sa_vb = (const float*)d_in[8];
  const float* sa_ow = (const float*)d_in[9];  const float* sa_ob = (const float*)d_in[10];
  const float* t2i_qw = (const float*)d_in[11]; const float* t2i_qb = (const float*)d_in[12];
  const float* t2i_kw = (const float*)d_in[13]; const float* t2i_kb = (const float*)d_in[14];
  const float* t2i_vw = (const float*)d_in[15]; const float* t2i_vb = (const float*)d_in[16];
  const float* t2i_ow = (const float*)d_in[17]; const float* t2i_ob = (const float*)d_in[18];
  const float* i2t_qw = (const float*)d_in[19]; const float* i2t_qb = (const float*)d_in[20];
  const float* i2t_kw = (const float*)d_in[21]; const float* i2t_kb = (const float*)d_in[22];
  const float* i2t_vw = (const float*)d_in[23]; const float* i2t_vb = (const float*)d_in[24];
  const float* i2t_ow = (const float*)d_in[25]; const float* i2t_ob = (const float*)d_in[26];
  const float* mlp_w1 = (const float*)d_in[27]; const float* mlp_b1 = (const float*)d_in[28];
  const float* mlp_w2 = (const float*)d_in[29]; const float* mlp_b2 = (const float*)d_in[30];
  const float* ln1_g = (const float*)d_in[31]; const float* ln1_b = (const float*)d_in[32];
  const float* ln2_g = (const float*)d_in[33]; const float* ln2_b = (const float*)d_in[34];
  const float* ln3_g = (const float*)d_in[35]; const float* ln3_b = (const float*)d_in[36];
  const float* ln4_g = (const float*)d_in[37]; const float* ln4_b = (const float*)d_in[38];

  float* out_q = (float*)d_out;            // [1024,256] f32
  float* out_k = out_q + 262144;           // [131072,256] f32 (128 MiB)

  // out_k region as scratch (all dead before k_gemm_ln writes f32):
  u16* kvbuf  = (u16*)out_k;               // [131072][256] bf16 @ [0,64MiB)
  u16* qb_big = (u16*)out_k + 33554432;    // [131072][128] bf16 @ [64,96MiB)
  float* t2i_part = (float*)((u16*)out_k + 50331648);  // @ [96,~114MiB)

  char* ws = (char*)d_ws;
  size_t off = 0;
  auto alloc = [&](size_t bytes) -> char* {
    char* p = ws + off;
    off += (bytes + 255) & ~(size_t)255;
    return p;
  };
  u16* wt_saqkv = (u16*)alloc(768 * 256 * 2);
  u16* wt_saow  = (u16*)alloc(256 * 256 * 2);
  u16* wt_t2iq  = (u16*)alloc(128 * 256 * 2);
  u16* wt_kvq   = (u16*)alloc(384 * 256 * 2);   // t2i_k | t2i_v | i2t_q  ^T
  u16* wt_t2io  = (u16*)alloc(256 * 128 * 2);
  u16* wt_i2tk  = (u16*)alloc(128 * 256 * 2);
  u16* wt_i2tv  = (u16*)alloc(128 * 256 * 2);
  u16* wt_i2to  = (u16*)alloc(256 * 128 * 2);
  u16* wt_w1    = (u16*)alloc(2048 * 256 * 2);
  u16* wt_w2    = (u16*)alloc(256 * 2048 * 2);
  float* b_saqkv = (float*)alloc(768 * 4);
  float* b_kvq   = (float*)alloc(384 * 4);
  float* q0f = (float*)alloc(262144 * 4);
  float* q1f = (float*)alloc(262144 * 4);
  float* q2f = (float*)alloc(262144 * 4);
  u16* q0b   = (u16*)alloc(262144 * 2);
  u16* qkvs  = (u16*)alloc(786432 * 2);
  u16* attn1 = (u16*)alloc(262144 * 2);
  u16* o1    = (u16*)alloc(262144 * 2);
  u16* q1pe  = (u16*)alloc(262144 * 2);
  u16* qt    = (u16*)alloc(131072 * 2);
  u16* at2   = (u16*)alloc(131072 * 2);
  u16* o2    = (u16*)alloc(262144 * 2);
  u16* q2b   = (u16*)alloc(262144 * 2);
  u16* hbuf  = (u16*)alloc(2097152 * 2);
  u16* mo    = (u16*)alloc(262144 * 2);
  u16* q3b   = (u16*)alloc(262144 * 2);
  u16* q3pe  = (u16*)alloc(262144 * 2);
  u16* kc    = (u16*)alloc(131072 * 2);
  u16* vc    = (u16*)alloc(131072 * 2);
  u16* ab_big = (u16*)alloc((size_t)16777216 * 2);  // [131072][128] bf16, 32MB

  // --- 1. weight prep ---
  TArgs ta{};
  int nb = 0, id = 0;
  auto addT = [&](const float* s, void* d, int K, int N, int mode) {
    ta.d[id].src = s; ta.d[id].dst = d; ta.d[id].K = K; ta.d[id].N = N;
    ta.d[id].mode = mode; ta.d[id].blk0 = nb;
    nb += (K * N + 255) / 256;
    ++id;
  };
  addT(sa_qw, wt_saqkv, 256, 256, 0);
  addT(sa_kw, wt_saqkv + 256 * 256, 256, 256, 0);
  addT(sa_vw, wt_saqkv + 512 * 256, 256, 256, 0);
  addT(sa_ow, wt_saow, 256, 256, 0);
  addT(t2i_qw, wt_t2iq, 256, 128, 0);
  addT(t2i_kw, wt_kvq, 256, 128, 0);
  addT(t2i_vw, wt_kvq + 128 * 256, 256, 128, 0);
  addT(i2t_qw, wt_kvq + 256 * 256, 256, 128, 0);
  addT(t2i_ow, wt_t2io, 128, 256, 0);
  addT(i2t_kw, wt_i2tk, 256, 128, 0);
  addT(i2t_vw, wt_i2tv, 256, 128, 0);
  addT(i2t_ow, wt_i2to, 128, 256, 0);
  addT(mlp_w1, wt_w1, 256, 2048, 0);
  addT(mlp_w2, wt_w2, 2048, 256, 0);
  addT(sa_qb, b_saqkv, 1, 256, 1);
  addT(sa_kb, b_saqkv + 256, 1, 256, 1);
  addT(sa_vb, b_saqkv + 512, 1, 256, 1);
  addT(t2i_kb, b_kvq, 1, 128, 1);
  addT(t2i_vb, b_kvq + 128, 1, 128, 1);
  addT(i2t_qb, b_kvq + 256, 1, 128, 1);
  ta.n = id;
  k_trans<<<nb, 256, 0, stream>>>(ta);

  // --- 2. q0 = queries + pe ---
  k_addpe<<<1024, 256, 0, stream>>>(queries, qpe, q0f, q0b);
  // --- 3. self-attn QKV (fused, N=768) ---
  k_gemm<false><<<dim3(6, 8), 256, 0, stream>>>(q0b, wt_saqkv, b_saqkv,
                                                qkvs, 768, 256);
  // --- 4. self-attention ---
  k_attn_sa<<<256, 64, 0, stream>>>(qkvs, attn1);
  // --- 5. sa out proj ---
  k_gemm<false><<<dim3(2, 8), 256, 0, stream>>>(attn1, wt_saow, sa_ob,
                                                o1, 256, 256);
  // --- 6. ln1 (+pe for t2i Q input) ---
  k_addln_small<<<256, 256, 0, stream>>>(q0f, o1, ln1_g, ln1_b, q1f, nullptr,
                                         qpe, q1pe);
  // --- 7. t2i Q proj ---
  k_gemm<false><<<dim3(1, 8), 256, 0, stream>>>(q1pe, wt_t2iq, t2i_qb,
                                                qt, 128, 256);
  // --- 8. fused keys projections (barrier-free, A+W direct) ---
  k_gemm_kvq<<<1024, 512, 0, stream>>>(keys, wt_kvq, b_kvq, kvbuf, qb_big);
  // --- 9. t2i attention: split-K partials + merge ---
  k_attn_t2i_part<<<dim3(32, 32), 128, 0, stream>>>(qt, kvbuf, t2i_part);
  k_attn_t2i_merge<<<256, 256, 0, stream>>>(t2i_part, at2);
  // --- 10. t2i out proj ---
  k_gemm<false><<<dim3(2, 8), 256, 0, stream>>>(at2, wt_t2io, t2i_ob,
                                                o2, 256, 128);
  // --- 11. ln2 ---
  k_addln_small<<<256, 256, 0, stream>>>(q1f, o2, ln2_g, ln2_b, q2f, q2b,
                                         nullptr, nullptr);
  // --- 12. MLP ---
  k_gemm<true><<<dim3(16, 8), 256, 0, stream>>>(q2b, wt_w1, mlp_b1,
                                                hbuf, 2048, 256);
  k_gemm<false><<<dim3(2, 8), 256, 0, stream>>>(hbuf, wt_w2, mlp_b2,
                                                mo, 256, 2048);
  // --- 13. ln3 -> f32 queries OUTPUT + bf16 copy + (y+pe) for i2t K ---
  k_addln_small<<<256, 256, 0, stream>>>(q2f, mo, ln3_g, ln3_b, out_q, q3b,
                                         qpe, q3pe);
  // --- 14. i2t small K/V projections ---
  k_gemm<false><<<dim3(1, 8), 256, 0, stream>>>(q3pe, wt_i2tk, i2t_kb,
                                                kc, 128, 256);
  k_gemm<false><<<dim3(1, 8), 256, 0, stream>>>(q3b, wt_i2tv, i2t_vb,
                                                vc, 128, 256);
  // --- 15. i2t attention: qb_big -> ab_big (ws) ---
  k_attn_i2t<<<4096, 256, 0, stream>>>(qb_big, kc, vc, ab_big);
  // --- 16. i2t out proj + keys residual + ln4 -> f32 out_k (W from L2) ---
  k_gemm_ln<<<2048, 256, 0, stream>>>(ab_big, wt_i2to, i2t_ob, keys,
                                      ln4_g, ln4_b, out_k);
}

// Round 16
// 550.916 us; speedup vs baseline: 1.1496x; 1.1496x over previous
//
#include <hip/hip_runtime.h>

typedef unsigned short u16;
typedef __attribute__((ext_vector_type(8))) short s16x8;   // 8 bf16 (4 VGPR)
typedef __attribute__((ext_vector_type(4))) float f32x4;
typedef __attribute__((ext_vector_type(8))) unsigned short u16x8;

__device__ __forceinline__ float b2f(u16 u) {
  union { unsigned int i; float f; } v; v.i = ((unsigned int)u) << 16; return v.f;
}
__device__ __forceinline__ u16 f2b(float f) {
  union { float f; unsigned int i; } v; v.f = f;
  unsigned int r = v.i + 0x7FFFu + ((v.i >> 16) & 1u);   // RNE
  return (u16)(r >> 16);
}
__device__ __forceinline__ int pk2(float a, float b) {
  return (int)f2b(a) | ((int)f2b(b) << 16);
}

// ---------------------------------------------------------------------------
// MFMA GEMM: C(bf16)[M,N] = A[M,K] @ W[K,N] + bias(f32). Wt = W^T bf16 [N][K].
// BM=BN=128, BK=64, 4 waves (2x2). A+W staged in LDS, XOR-swizzled.
// (r12-verbatim.)
// ---------------------------------------------------------------------------
template<bool RELU>
__global__ void __launch_bounds__(256) k_gemm(
    const u16* __restrict__ A, const u16* __restrict__ Wt,
    const float* __restrict__ bias, u16* __restrict__ C, int N, int K)
{
  __shared__ int4 smem4[2048];             // 32 KB
  char* AsB = (char*)smem4;
  char* WsB = (char*)smem4 + 16384;
  const int t = threadIdx.x;
  const int lane = t & 63, wid = t >> 6;
  const int wm = wid >> 1, wn = wid & 1;
  const int l16 = lane & 15, lhi = lane >> 4;
  const int bCol = blockIdx.x * 128;
  const int bRow = blockIdx.y * 128;

  f32x4 acc[4][4];
#pragma unroll
  for (int i = 0; i < 4; ++i)
#pragma unroll
    for (int j = 0; j < 4; ++j) acc[i][j] = (f32x4){0.f, 0.f, 0.f, 0.f};

  const int nk = K >> 6;
  for (int kt = 0; kt < nk; ++kt) {
    const int k0 = kt << 6;
    int4 av[4], wv[4];
#pragma unroll
    for (int i = 0; i < 4; ++i) {
      int L = i * 4096 + t * 16;
      int r = L >> 7, cl = (L >> 4) & 7;
      av[i] = *(const int4*)(A + (size_t)(bRow + r) * K + k0 + cl * 8);
      wv[i] = *(const int4*)(Wt + (size_t)(bCol + r) * K + k0 + cl * 8);
    }
    if (kt) __syncthreads();
#pragma unroll
    for (int i = 0; i < 4; ++i) {
      int L = i * 4096 + t * 16;
      int r = L >> 7, cl = (L >> 4) & 7;
      int off = r * 128 + ((cl ^ (r & 7)) << 4);
      *(int4*)(AsB + off) = av[i];
      *(int4*)(WsB + off) = wv[i];
    }
    __syncthreads();
#pragma unroll
    for (int kk = 0; kk < 2; ++kk) {
      s16x8 af[4], bfr[4];
#pragma unroll
      for (int mt = 0; mt < 4; ++mt) {
        int r = wm * 64 + mt * 16 + l16;
        int ch = kk * 4 + lhi;
        af[mt] = *(const s16x8*)(AsB + r * 128 + ((ch ^ (r & 7)) << 4));
      }
#pragma unroll
      for (int nt = 0; nt < 4; ++nt) {
        int r = wn * 64 + nt * 16 + l16;
        int ch = kk * 4 + lhi;
        bfr[nt] = *(const s16x8*)(WsB + r * 128 + ((ch ^ (r & 7)) << 4));
      }
#pragma unroll
      for (int mt = 0; mt < 4; ++mt)
#pragma unroll
        for (int nt = 0; nt < 4; ++nt)
          acc[mt][nt] = __builtin_amdgcn_mfma_f32_16x16x32_bf16(
              af[mt], bfr[nt], acc[mt][nt], 0, 0, 0);
    }
  }
#pragma unroll
  for (int mt = 0; mt < 4; ++mt) {
#pragma unroll
    for (int nt = 0; nt < 4; ++nt) {
      int cg = bCol + wn * 64 + nt * 16 + l16;
      float bv = bias[cg];
#pragma unroll
      for (int rg = 0; rg < 4; ++rg) {
        int rgl = bRow + wm * 64 + mt * 16 + lhi * 4 + rg;
        float v = acc[mt][nt][rg] + bv;
        if (RELU) v = fmaxf(v, 0.f);
        C[(size_t)rgl * N + cg] = f2b(v);
      }
    }
  }
}

// ---------------------------------------------------------------------------
// Fused queries phase 1 (per batch, 32 blocks x 256 threads):
//   q0 = queries+pe -> QKV proj -> self-attn -> sa-out + ln1 (+pe) ->
//   t2i Q proj. All intermediates in LDS; weights direct from L2.
// Outputs: q1f f32 [1024][256] (ln2 residual), qt bf16 [1024][128].
// ---------------------------------------------------------------------------
__global__ void __launch_bounds__(256) k_qphase1(
    const float* __restrict__ queries, const float* __restrict__ qpe,
    const u16* __restrict__ Wqkv,   // [768][256] bf16
    const float* __restrict__ bqkv, // [768]
    const u16* __restrict__ Wo,     // [256][256] bf16
    const float* __restrict__ ob,   // [256]
    const float* __restrict__ g1, const float* __restrict__ b1,
    const u16* __restrict__ Wq2,    // [128][256] bf16
    const float* __restrict__ qb2,  // [128]
    float* __restrict__ q1f, u16* __restrict__ qt)
{
  __shared__ float q0f[32][260];      // ~33 KB (stride 260 -> 2-way banks)
  __shared__ u16 qkv[32][776];        // ~48.5 KB
  __shared__ u16 atb[32][264];        // ~16.5 KB (attn out, then q1pe)
  __shared__ float rs[32][4], rq[32][4];
  const int b = blockIdx.x;
  const int t = threadIdx.x;
  const int lane = t & 63, w = t >> 6;
  const int l16 = lane & 15, lhi = lane >> 4;

  // --- stage 1: q0 = queries + pe (f32, LDS) ---
  {
    const float4* qg = (const float4*)(queries + (size_t)b * 8192);
    const float4* pg = (const float4*)(qpe + (size_t)b * 8192);
    for (int i = t; i < 2048; i += 256) {
      int row = i >> 6, c4 = (i & 63) * 4;
      float4 qv = qg[i], pv = pg[i];
      *(float4*)&q0f[row][c4] =
          (float4){qv.x + pv.x, qv.y + pv.y, qv.z + pv.z, qv.w + pv.w};
    }
  }
  __syncthreads();

  // --- stage 2: QKV = q0 @ Wqkv + bqkv -> qkv LDS (bf16) ---
  {
    f32x4 acc[2][12];
#pragma unroll
    for (int i = 0; i < 2; ++i)
#pragma unroll
      for (int j = 0; j < 12; ++j) acc[i][j] = (f32x4){0.f, 0.f, 0.f, 0.f};
#pragma unroll
    for (int kk = 0; kk < 8; ++kk) {
      const int ko = kk * 32 + lhi * 8;
      s16x8 af[2], bfr[12];
#pragma unroll
      for (int mt = 0; mt < 2; ++mt) {
        const float* ap = &q0f[mt * 16 + l16][ko];
        float4 x = *(const float4*)ap;
        float4 y = *(const float4*)(ap + 4);
        int4 p = (int4){pk2(x.x, x.y), pk2(x.z, x.w),
                        pk2(y.x, y.y), pk2(y.z, y.w)};
        af[mt] = *(s16x8*)&p;
      }
#pragma unroll
      for (int nt = 0; nt < 12; ++nt) {
        int row = w * 192 + nt * 16 + l16;
        bfr[nt] = *(const s16x8*)(Wqkv + (size_t)row * 256 + ko);
      }
#pragma unroll
      for (int mt = 0; mt < 2; ++mt)
#pragma unroll
        for (int nt = 0; nt < 12; ++nt)
          acc[mt][nt] = __builtin_amdgcn_mfma_f32_16x16x32_bf16(
              af[mt], bfr[nt], acc[mt][nt], 0, 0, 0);
    }
#pragma unroll
    for (int mt = 0; mt < 2; ++mt)
#pragma unroll
      for (int nt = 0; nt < 12; ++nt) {
        int cg = w * 192 + nt * 16 + l16;
        float bv = bqkv[cg];
#pragma unroll
        for (int rg = 0; rg < 4; ++rg)
          qkv[mt * 16 + lhi * 4 + rg][cg] = f2b(acc[mt][nt][rg] + bv);
      }
  }
  __syncthreads();

  // --- stage 3: self-attention, thread = (q, h), d=32, scale 1/sqrt(32) ---
  {
    int q = t >> 3, h = t & 7;
    float Qh[32];
#pragma unroll
    for (int c = 0; c < 4; ++c) {
      u16x8 v = *(const u16x8*)&qkv[q][h * 32 + c * 8];
#pragma unroll
      for (int e = 0; e < 8; ++e) Qh[c * 8 + e] = b2f(v[e]);
    }
    float s[32], mx = -INFINITY;
#pragma unroll 4
    for (int j = 0; j < 32; ++j) {
      float a = 0.f;
#pragma unroll
      for (int c = 0; c < 4; ++c) {
        u16x8 v = *(const u16x8*)&qkv[j][256 + h * 32 + c * 8];
#pragma unroll
        for (int e = 0; e < 8; ++e) a += Qh[c * 8 + e] * b2f(v[e]);
      }
      s[j] = a * 0.17677669529663687f;
      mx = fmaxf(mx, s[j]);
    }
    float sum = 0.f;
#pragma unroll
    for (int j = 0; j < 32; ++j) { s[j] = __expf(s[j] - mx); sum += s[j]; }
    float o[32];
#pragma unroll
    for (int d = 0; d < 32; ++d) o[d] = 0.f;
#pragma unroll 4
    for (int j = 0; j < 32; ++j) {
      float p = s[j];
#pragma unroll
      for (int c = 0; c < 4; ++c) {
        u16x8 v = *(const u16x8*)&qkv[j][512 + h * 32 + c * 8];
#pragma unroll
        for (int e = 0; e < 8; ++e) o[c * 8 + e] += p * b2f(v[e]);
      }
    }
    float inv = 1.f / sum;
#pragma unroll
    for (int d = 0; d < 32; ++d) atb[q][h * 32 + d] = f2b(o[d] * inv);
  }
  __syncthreads();

  // --- stage 4: sa-out proj + residual(q0f) + ln1; y->q1f, y+pe->atb ---
  float yv[2][4][4];                  // [mt][nt][rg]
  {
    f32x4 acc[2][4];
#pragma unroll
    for (int i = 0; i < 2; ++i)
#pragma unroll
      for (int j = 0; j < 4; ++j) acc[i][j] = (f32x4){0.f, 0.f, 0.f, 0.f};
#pragma unroll
    for (int kk = 0; kk < 8; ++kk) {
      const int ko = kk * 32 + lhi * 8;
      s16x8 af[2], bfr[4];
#pragma unroll
      for (int mt = 0; mt < 2; ++mt)
        af[mt] = *(const s16x8*)&atb[mt * 16 + l16][ko];
#pragma unroll
      for (int nt = 0; nt < 4; ++nt) {
        int row = w * 64 + nt * 16 + l16;
        bfr[nt] = *(const s16x8*)(Wo + (size_t)row * 256 + ko);
      }
#pragma unroll
      for (int mt = 0; mt < 2; ++mt)
#pragma unroll
        for (int nt = 0; nt < 4; ++nt)
          acc[mt][nt] = __builtin_amdgcn_mfma_f32_16x16x32_bf16(
              af[mt], bfr[nt], acc[mt][nt], 0, 0, 0);
    }
    // v = acc + bias + q0 residual; per-row partial sums over wave's 64 cols
#pragma unroll
    for (int mt = 0; mt < 2; ++mt) {
#pragma unroll
      for (int rg = 0; rg < 4; ++rg) {
        int row = mt * 16 + lhi * 4 + rg;
        float ps = 0.f, pq = 0.f;
#pragma unroll
        for (int nt = 0; nt < 4; ++nt) {
          int cg = w * 64 + nt * 16 + l16;
          float v = acc[mt][nt][rg] + ob[cg] + q0f[row][cg];
          yv[mt][nt][rg] = v;
          ps += v; pq += v * v;
        }
#pragma unroll
        for (int msk = 1; msk < 16; msk <<= 1) {
          ps += __shfl_xor(ps, msk);
          pq += __shfl_xor(pq, msk);
        }
        if (l16 == 0) { rs[row][w] = ps; rq[row][w] = pq; }
      }
    }
  }
  __syncthreads();
  {
#pragma unroll
    for (int mt = 0; mt < 2; ++mt) {
#pragma unroll
      for (int rg = 0; rg < 4; ++rg) {
        int row = mt * 16 + lhi * 4 + rg;
        float ts = rs[row][0] + rs[row][1] + rs[row][2] + rs[row][3];
        float tq = rq[row][0] + rq[row][1] + rq[row][2] + rq[row][3];
        float mean = ts * (1.f / 256.f);
        float var = tq * (1.f / 256.f) - mean * mean;
        float rstd = rsqrtf(var + 1e-5f);
#pragma unroll
        for (int nt = 0; nt < 4; ++nt) {
          int cg = w * 64 + nt * 16 + l16;
          float y = (yv[mt][nt][rg] - mean) * rstd * g1[cg] + b1[cg];
          size_t gi = ((size_t)b * 32 + row) * 256 + cg;
          q1f[gi] = y;
          atb[row][cg] = f2b(y + qpe[gi]);   // q1pe (safe: post-barrier)
        }
      }
    }
  }
  __syncthreads();

  // --- stage 5: qt = q1pe @ Wq2 + qb2 -> global bf16 [*,128] ---
  {
    f32x4 acc[2][2];
#pragma unroll
    for (int i = 0; i < 2; ++i)
#pragma unroll
      for (int j = 0; j < 2; ++j) acc[i][j] = (f32x4){0.f, 0.f, 0.f, 0.f};
#pragma unroll
    for (int kk = 0; kk < 8; ++kk) {
      const int ko = kk * 32 + lhi * 8;
      s16x8 af[2], bfr[2];
#pragma unroll
      for (int mt = 0; mt < 2; ++mt)
        af[mt] = *(const s16x8*)&atb[mt * 16 + l16][ko];
#pragma unroll
      for (int nt = 0; nt < 2; ++nt) {
        int row = w * 32 + nt * 16 + l16;
        bfr[nt] = *(const s16x8*)(Wq2 + (size_t)row * 256 + ko);
      }
#pragma unroll
      for (int mt = 0; mt < 2; ++mt)
#pragma unroll
        for (int nt = 0; nt < 2; ++nt)
          acc[mt][nt] = __builtin_amdgcn_mfma_f32_16x16x32_bf16(
              af[mt], bfr[nt], acc[mt][nt], 0, 0, 0);
    }
#pragma unroll
    for (int mt = 0; mt < 2; ++mt)
#pragma unroll
      for (int nt = 0; nt < 2; ++nt) {
        int cg = w * 32 + nt * 16 + l16;
        float bv = qb2[cg];
#pragma unroll
        for (int rg = 0; rg < 4; ++rg) {
          int row = mt * 16 + lhi * 4 + rg;
          qt[((size_t)b * 32 + row) * 128 + cg] = f2b(acc[mt][nt][rg] + bv);
        }
      }
  }
}

// ---------------------------------------------------------------------------
// Fused keys projections (r12-verbatim, 123 us): A staged in LDS, W direct.
// ---------------------------------------------------------------------------
__global__ void __launch_bounds__(512, 2) k_gemm_kvq(
    const float* __restrict__ A, const u16* __restrict__ Wt,
    const float* __restrict__ bias, u16* __restrict__ KV, u16* __restrict__ QB)
{
  __shared__ char smem[49152];             // GEMM: A 16KB; epilogue: ldsO 48KB
  char* AsB = smem;
  const int t = threadIdx.x;
  const int lane = t & 63, wid = t >> 6;
  const int wm = wid >> 2, wn = wid & 3;   // 2 x 4 waves
  const int l16 = lane & 15, lhi = lane >> 4;
  const int bRow = blockIdx.x * 128;

  f32x4 acc[4][6];
#pragma unroll
  for (int i = 0; i < 4; ++i)
#pragma unroll
    for (int j = 0; j < 6; ++j) acc[i][j] = (f32x4){0.f, 0.f, 0.f, 0.f};

  for (int kt = 0; kt < 4; ++kt) {
    const int k0 = kt << 6;
    float4 a0r[2], a1r[2];
#pragma unroll
    for (int i = 0; i < 2; ++i) {
      int L = i * 8192 + t * 16;
      int r = L >> 7, cl = (L >> 4) & 7;
      const float* Af = A + (size_t)(bRow + r) * 256 + k0 + cl * 8;
      a0r[i] = *(const float4*)Af;
      a1r[i] = *(const float4*)(Af + 4);
    }
    if (kt) __syncthreads();
#pragma unroll
    for (int i = 0; i < 2; ++i) {
      int L = i * 8192 + t * 16;
      int r = L >> 7, cl = (L >> 4) & 7;
      int4 p = (int4){pk2(a0r[i].x, a0r[i].y), pk2(a0r[i].z, a0r[i].w),
                      pk2(a1r[i].x, a1r[i].y), pk2(a1r[i].z, a1r[i].w)};
      *(int4*)(AsB + r * 128 + ((cl ^ (r & 7)) << 4)) = p;
    }
    __syncthreads();
#pragma unroll
    for (int kk = 0; kk < 2; ++kk) {
      s16x8 af[4], bfr[6];
#pragma unroll
      for (int nt = 0; nt < 6; ++nt) {
        int row = wn * 96 + nt * 16 + l16;
        bfr[nt] = *(const s16x8*)(Wt + (size_t)row * 256 + k0 + kk * 32 + lhi * 8);
      }
#pragma unroll
      for (int mt = 0; mt < 4; ++mt) {
        int r = wm * 64 + mt * 16 + l16;
        int ch = kk * 4 + lhi;
        af[mt] = *(const s16x8*)(AsB + r * 128 + ((ch ^ (r & 7)) << 4));
      }
#pragma unroll
      for (int mt = 0; mt < 4; ++mt)
#pragma unroll
        for (int nt = 0; nt < 6; ++nt)
          acc[mt][nt] = __builtin_amdgcn_mfma_f32_16x16x32_bf16(
              af[mt], bfr[nt], acc[mt][nt], 0, 0, 0);
    }
  }
  u16* ldsO = (u16*)smem;                  // [64][384] u16 = 48KB
  for (int half = 0; half < 2; ++half) {
    __syncthreads();
    if (wm == half) {
#pragma unroll
      for (int mt = 0; mt < 4; ++mt) {
#pragma unroll
        for (int nt = 0; nt < 6; ++nt) {
          int cg = wn * 96 + nt * 16 + l16;
          float bv = bias[cg];
#pragma unroll
          for (int rg = 0; rg < 4; ++rg) {
            int r = mt * 16 + lhi * 4 + rg;
            ldsO[r * 384 + cg] = f2b(acc[mt][nt][rg] + bv);
          }
        }
      }
    }
    __syncthreads();
#pragma unroll
    for (int i = 0; i < 6; ++i) {
      int chunk = i * 512 + t;
      int r = chunk / 48, c8 = chunk - r * 48;
      int row = bRow + half * 64 + r;
      int4 v = *(int4*)(ldsO + r * 384 + c8 * 8);
      if (c8 < 32) *(int4*)(KV + (size_t)row * 256 + c8 * 8) = v;
      else         *(int4*)(QB + (size_t)row * 128 + (c8 - 32) * 8) = v;
    }
  }
}

// ---------------------------------------------------------------------------
// i2t out-proj + residual + LN4 (r12-verbatim). BM=64, W direct, grid M/64.
// ---------------------------------------------------------------------------
__global__ void __launch_bounds__(256) k_gemm_ln(
    const u16* __restrict__ A, const u16* __restrict__ Wt,
    const float* __restrict__ bias, const float* __restrict__ res,
    const float* __restrict__ g, const float* __restrict__ bl,
    float* __restrict__ out)
{
  __shared__ int4 smem4[512];              // 8 KB A-tile
  __shared__ float rsum[2][32][2], rsq[2][32][2];
  char* AsB = (char*)smem4;
  const int t = threadIdx.x;
  const int lane = t & 63, wid = t >> 6;
  const int wm = wid >> 1, wn = wid & 1;
  const int l16 = lane & 15, lhi = lane >> 4;
  const int bRow = blockIdx.x * 64;

  f32x4 acc[2][8];
#pragma unroll
  for (int i = 0; i < 2; ++i)
#pragma unroll
    for (int j = 0; j < 8; ++j) acc[i][j] = (f32x4){0.f, 0.f, 0.f, 0.f};

  for (int kt = 0; kt < 2; ++kt) {
    const int k0 = kt << 6;
    int4 av[2];
#pragma unroll
    for (int i = 0; i < 2; ++i) {          // A: 64 x 64
      int L = i * 4096 + t * 16;
      int r = L >> 7, cl = (L >> 4) & 7;
      av[i] = *(const int4*)(A + (size_t)(bRow + r) * 128 + k0 + cl * 8);
    }
    if (kt) __syncthreads();
#pragma unroll
    for (int i = 0; i < 2; ++i) {
      int L = i * 4096 + t * 16;
      int r = L >> 7, cl = (L >> 4) & 7;
      *(int4*)(AsB + r * 128 + ((cl ^ (r & 7)) << 4)) = av[i];
    }
    __syncthreads();
#pragma unroll
    for (int kk = 0; kk < 2; ++kk) {
      s16x8 af[2], bfr[8];
#pragma unroll
      for (int nt = 0; nt < 8; ++nt) {
        int row = wn * 128 + nt * 16 + l16;
        bfr[nt] = *(const s16x8*)(Wt + (size_t)row * 128 + k0 + kk * 32 + lhi * 8);
      }
#pragma unroll
      for (int mt = 0; mt < 2; ++mt) {
        int r = wm * 32 + mt * 16 + l16;
        int ch = kk * 4 + lhi;
        af[mt] = *(const s16x8*)(AsB + r * 128 + ((ch ^ (r & 7)) << 4));
      }
#pragma unroll
      for (int mt = 0; mt < 2; ++mt)
#pragma unroll
        for (int nt = 0; nt < 8; ++nt)
          acc[mt][nt] = __builtin_amdgcn_mfma_f32_16x16x32_bf16(
              af[mt], bfr[nt], acc[mt][nt], 0, 0, 0);
    }
  }
#pragma unroll
  for (int mt = 0; mt < 2; ++mt) {
#pragma unroll
    for (int nt = 0; nt < 8; ++nt) {
      int cg = wn * 128 + nt * 16 + l16;
      float bv = bias[cg];
#pragma unroll
      for (int rg = 0; rg < 4; ++rg) {
        int row = bRow + wm * 32 + mt * 16 + lhi * 4 + rg;
        acc[mt][nt][rg] += bv + res[(size_t)row * 256 + cg];
      }
    }
  }
#pragma unroll
  for (int mt = 0; mt < 2; ++mt) {
#pragma unroll
    for (int rg = 0; rg < 4; ++rg) {
      float ps = 0.f, pq = 0.f;
#pragma unroll
      for (int nt = 0; nt < 8; ++nt) {
        float v = acc[mt][nt][rg];
        ps += v; pq += v * v;
      }
#pragma unroll
      for (int msk = 1; msk < 16; msk <<= 1) {
        ps += __shfl_xor(ps, msk);
        pq += __shfl_xor(pq, msk);
      }
      if (l16 == 0) {
        int rl = mt * 16 + lhi * 4 + rg;
        rsum[wm][rl][wn] = ps;
        rsq[wm][rl][wn] = pq;
      }
    }
  }
  __syncthreads();
#pragma unroll
  for (int mt = 0; mt < 2; ++mt) {
#pragma unroll
    for (int rg = 0; rg < 4; ++rg) {
      int rl = mt * 16 + lhi * 4 + rg;
      float ts = rsum[wm][rl][0] + rsum[wm][rl][1];
      float tq = rsq[wm][rl][0] + rsq[wm][rl][1];
      float mean = ts * (1.f / 256.f);
      float var = tq * (1.f / 256.f) - mean * mean;
      float rstd = rsqrtf(var + 1e-5f);
      int row = bRow + wm * 32 + rl;
#pragma unroll
      for (int nt = 0; nt < 8; ++nt) {
        int cg = wn * 128 + nt * 16 + l16;
        out[(size_t)row * 256 + cg] =
            (acc[mt][nt][rg] - mean) * rstd * g[cg] + bl[cg];
      }
    }
  }
}

// ---------------------------------------------------------------------------
struct TDesc { const float* src; void* dst; int K; int N; int mode; int blk0; };
struct TArgs { TDesc d[24]; int n; };

__global__ void __launch_bounds__(256) k_trans(TArgs a)
{
  int blk = blockIdx.x;
  int i = 0;
  while (i + 1 < a.n && blk >= a.d[i + 1].blk0) ++i;
  TDesc td = a.d[i];
  int e = (blk - td.blk0) * 256 + threadIdx.x;
  int tot = td.K * td.N;
  if (e >= tot) return;
  if (td.mode == 0) {
    int k = e / td.N, n = e - k * td.N;
    ((u16*)td.dst)[(size_t)n * td.K + k] = f2b(td.src[e]);
  } else {
    ((float*)td.dst)[e] = td.src[e];
  }
}

// ---------------------------------------------------------------------------
// t2i partial attention (split-K flash). Grid (32 chunks, 32 b), 128 threads.
// ---------------------------------------------------------------------------
__global__ void __launch_bounds__(128) k_attn_t2i_part(
    const u16* __restrict__ Qt, const u16* __restrict__ KV,
    float* __restrict__ part)
{
  __shared__ int4 kvs[4096];               // 64 KB = 128 rows x 256 u16
  int c = blockIdx.x, b = blockIdx.y;
  int tid = threadIdx.x;
  const int4* src = (const int4*)(KV + ((size_t)b * 4096 + c * 128) * 256);
  for (int i = tid; i < 4096; i += 128) kvs[i] = src[i];
  __syncthreads();
  int qp = tid >> 3, h = tid & 7;
  const u16* lds = (const u16*)kvs;

  float q0[16], q1[16];
  {
    const u16* p0 = Qt + (size_t)(b * 32 + qp) * 128 + h * 16;
    const u16* p1 = Qt + (size_t)(b * 32 + qp + 16) * 128 + h * 16;
    u16x8 a0 = *(const u16x8*)p0, b0 = *(const u16x8*)(p0 + 8);
    u16x8 a1 = *(const u16x8*)p1, b1 = *(const u16x8*)(p1 + 8);
#pragma unroll
    for (int e = 0; e < 8; ++e) {
      q0[e] = b2f(a0[e]); q0[8 + e] = b2f(b0[e]);
      q1[e] = b2f(a1[e]); q1[8 + e] = b2f(b1[e]);
    }
  }
  float m0 = -INFINITY, s0 = 0.f, m1 = -INFINITY, s1 = 0.f;
  float acc0[16], acc1[16];
#pragma unroll
  for (int d = 0; d < 16; ++d) { acc0[d] = 0.f; acc1[d] = 0.f; }

  for (int j = 0; j < 128; ++j) {
    const u16* kr = lds + j * 256 + h * 16;
    u16x8 ka = *(const u16x8*)kr;
    u16x8 kb = *(const u16x8*)(kr + 8);
    float l0 = 0.f, l1 = 0.f;
#pragma unroll
    for (int e = 0; e < 8; ++e) {
      float klo = b2f(ka[e]), khi = b2f(kb[e]);
      l0 += q0[e] * klo + q0[8 + e] * khi;
      l1 += q1[e] * klo + q1[8 + e] * khi;
    }
    l0 *= 0.25f; l1 *= 0.25f;
    const u16* vr = kr + 128;
    u16x8 va = *(const u16x8*)vr;
    u16x8 vb = *(const u16x8*)(vr + 8);
    float nm0 = fmaxf(m0, l0), nm1 = fmaxf(m1, l1);
    float c0 = __expf(m0 - nm0), p0 = __expf(l0 - nm0);
    float c1 = __expf(m1 - nm1), p1 = __expf(l1 - nm1);
    s0 = s0 * c0 + p0; s1 = s1 * c1 + p1;
#pragma unroll
    for (int e = 0; e < 8; ++e) {
      float vlo = b2f(va[e]), vhi = b2f(vb[e]);
      acc0[e] = acc0[e] * c0 + p0 * vlo;
      acc0[8 + e] = acc0[8 + e] * c0 + p0 * vhi;
      acc1[e] = acc1[e] * c1 + p1 * vlo;
      acc1[8 + e] = acc1[8 + e] * c1 + p1 * vhi;
    }
    m0 = nm0; m1 = nm1;
  }
  float* r0 = part + (((size_t)(b * 32 + qp) * 8 + h) * 32 + c) * 18;
  float* r1 = part + (((size_t)(b * 32 + qp + 16) * 8 + h) * 32 + c) * 18;
#pragma unroll
  for (int d = 0; d < 16; ++d) { r0[d] = acc0[d]; r1[d] = acc1[d]; }
  r0[16] = m0; r0[17] = s0;
  r1[16] = m1; r1[17] = s1;
}

// ---------------------------------------------------------------------------
__global__ void __launch_bounds__(256) k_attn_t2i_merge(
    const float* __restrict__ part, u16* __restrict__ out)
{
  int b = blockIdx.x >> 3, h = blockIdx.x & 7;
  int q = threadIdx.x >> 3, ds = threadIdx.x & 7;
  const float* base = part + (((size_t)(b * 32 + q) * 8 + h) * 32) * 18;
  float mg = -INFINITY;
#pragma unroll 4
  for (int c = 0; c < 32; ++c) mg = fmaxf(mg, base[c * 18 + 16]);
  float sg = 0.f, a0 = 0.f, a1 = 0.f;
#pragma unroll 4
  for (int c = 0; c < 32; ++c) {
    const float* rec = base + c * 18;
    float w = __expf(rec[16] - mg);
    sg += rec[17] * w;
    a0 += rec[ds * 2] * w;
    a1 += rec[ds * 2 + 1] * w;
  }
  float inv = 1.f / sg;
  u16* op = out + (size_t)(b * 32 + q) * 128 + h * 16 + ds * 2;
  op[0] = f2b(a0 * inv);
  op[1] = f2b(a1 * inv);
}

// ---------------------------------------------------------------------------
__global__ void __launch_bounds__(256) k_attn_i2t(
    const u16* __restrict__ Qb, const u16* __restrict__ Kc,
    const u16* __restrict__ Vc, u16* __restrict__ out)
{
  __shared__ float Kl[32][132], Vl[32][132];
  int blk = blockIdx.x;
  int b = blk >> 7;
  int r0 = (blk & 127) * 32;
  for (int idx = threadIdx.x; idx < 4096; idx += 256) {
    int j = idx >> 7, c = idx & 127;
    Kl[j][c] = b2f(Kc[(size_t)(b * 32 + j) * 128 + c]);
    Vl[j][c] = b2f(Vc[(size_t)(b * 32 + j) * 128 + c]);
  }
  __syncthreads();
  int lr = threadIdx.x >> 3, h = threadIdx.x & 7;
  size_t row = (size_t)b * 4096 + r0 + lr;
  const u16* qp = Qb + row * 128 + h * 16;
  float q[16];
  {
    u16x8 qa = *(const u16x8*)qp;
    u16x8 qb2 = *(const u16x8*)(qp + 8);
#pragma unroll
    for (int e = 0; e < 8; ++e) { q[e] = b2f(qa[e]); q[8 + e] = b2f(qb2[e]); }
  }
  float lg[32];
  float mx = -INFINITY;
#pragma unroll
  for (int j = 0; j < 32; ++j) {
    float a = 0.f;
#pragma unroll
    for (int d = 0; d < 16; ++d) a += q[d] * Kl[j][h * 16 + d];
    lg[j] = a * 0.25f;
    mx = fmaxf(mx, lg[j]);
  }
  float sum = 0.f;
#pragma unroll
  for (int j = 0; j < 32; ++j) { lg[j] = __expf(lg[j] - mx); sum += lg[j]; }
  float acc[16];
#pragma unroll
  for (int d = 0; d < 16; ++d) acc[d] = 0.f;
#pragma unroll
  for (int j = 0; j < 32; ++j) {
    float p = lg[j];
#pragma unroll
    for (int d = 0; d < 16; ++d) acc[d] += p * Vl[j][h * 16 + d];
  }
  float inv = 1.f / sum;
  u16* op = out + row * 128 + h * 16;
#pragma unroll
  for (int d = 0; d < 16; ++d) op[d] = f2b(acc[d] * inv);
}

// ---------------------------------------------------------------------------
__global__ void __launch_bounds__(256) k_addln_small(
    const float* __restrict__ res, const u16* __restrict__ delta,
    const float* __restrict__ g, const float* __restrict__ bb,
    float* outf, u16* outb, const float* pe, u16* outpe)
{
  int row = blockIdx.x * 4 + (threadIdx.x >> 6);
  int lane = threadIdx.x & 63;
  size_t base = (size_t)row * 256 + lane * 4;
  float4 xv = *(const float4*)(res + base);
  ushort4 dv = *(const ushort4*)(delta + base);
  float v0 = xv.x + b2f(dv.x), v1 = xv.y + b2f(dv.y);
  float v2 = xv.z + b2f(dv.z), v3 = xv.w + b2f(dv.w);
  float sum = v0 + v1 + v2 + v3;
  float sq = v0 * v0 + v1 * v1 + v2 * v2 + v3 * v3;
#pragma unroll
  for (int msk = 1; msk < 64; msk <<= 1) {
    sum += __shfl_xor(sum, msk);
    sq += __shfl_xor(sq, msk);
  }
  float mean = sum * (1.f / 256.f);
  float var = sq * (1.f / 256.f) - mean * mean;
  float rstd = rsqrtf(var + 1e-5f);
  float4 gv = *(const float4*)(g + lane * 4);
  float4 bv = *(const float4*)(bb + lane * 4);
  float y0 = (v0 - mean) * rstd * gv.x + bv.x;
  float y1 = (v1 - mean) * rstd * gv.y + bv.y;
  float y2 = (v2 - mean) * rstd * gv.z + bv.z;
  float y3 = (v3 - mean) * rstd * gv.w + bv.w;
  if (outf) { float4 o{y0, y1, y2, y3}; *(float4*)(outf + base) = o; }
  if (outb) {
    ushort4 o{f2b(y0), f2b(y1), f2b(y2), f2b(y3)};
    *(ushort4*)(outb + base) = o;
  }
  if (outpe) {
    float4 pv = *(const float4*)(pe + base);
    ushort4 o{f2b(y0 + pv.x), f2b(y1 + pv.y), f2b(y2 + pv.z), f2b(y3 + pv.w)};
    *(ushort4*)(outpe + base) = o;
  }
}

// ---------------------------------------------------------------------------
extern "C" void kernel_launch(void* const* d_in, const int* in_sizes, int n_in,
                              void* d_out, int out_size, void* d_ws, size_t ws_size,
                              hipStream_t stream)
{
  (void)in_sizes; (void)n_in; (void)out_size; (void)ws_size;
  const float* queries = (const float*)d_in[0];
  const float* keys    = (const float*)d_in[1];
  const float* qpe     = (const float*)d_in[2];
  const float* sa_qw = (const float*)d_in[3];  const float* sa_qb = (const float*)d_in[4];
  const float* sa_kw = (const float*)d_in[5];  const float* sa_kb = (const float*)d_in[6];
  const float* sa_vw = (const float*)d_in[7];  const float* sa_vb = (const float*)d_in[8];
  const float* sa_ow = (const float*)d_in[9];  const float* sa_ob = (const float*)d_in[10];
  const float* t2i_qw = (const float*)d_in[11]; const float* t2i_qb = (const float*)d_in[12];
  const float* t2i_kw = (const float*)d_in[13]; const float* t2i_kb = (const float*)d_in[14];
  const float* t2i_vw = (const float*)d_in[15]; const float* t2i_vb = (const float*)d_in[16];
  const float* t2i_ow = (const float*)d_in[17]; const float* t2i_ob = (const float*)d_in[18];
  const float* i2t_qw = (const float*)d_in[19]; const float* i2t_qb = (const float*)d_in[20];
  const float* i2t_kw = (const float*)d_in[21]; const float* i2t_kb = (const float*)d_in[22];
  const float* i2t_vw = (const float*)d_in[23]; const float* i2t_vb = (const float*)d_in[24];
  const float* i2t_ow = (const float*)d_in[25]; const float* i2t_ob = (const float*)d_in[26];
  const float* mlp_w1 = (const float*)d_in[27]; const float* mlp_b1 = (const float*)d_in[28];
  const float* mlp_w2 = (const float*)d_in[29]; const float* mlp_b2 = (const float*)d_in[30];
  const float* ln1_g = (const float*)d_in[31]; const float* ln1_b = (const float*)d_in[32];
  const float* ln2_g = (const float*)d_in[33]; const float* ln2_b = (const float*)d_in[34];
  const float* ln3_g = (const float*)d_in[35]; const float* ln3_b = (const float*)d_in[36];
  const float* ln4_g = (const float*)d_in[37]; const float* ln4_b = (const float*)d_in[38];

  float* out_q = (float*)d_out;            // [1024,256] f32
  float* out_k = out_q + 262144;           // [131072,256] f32 (128 MiB)

  u16* kvbuf  = (u16*)out_k;               // [131072][256] bf16 @ [0,64MiB)
  u16* qb_big = (u16*)out_k + 33554432;    // [131072][128] bf16 @ [64,96MiB)
  float* t2i_part = (float*)((u16*)out_k + 50331648);  // @ [96,~114MiB)

  char* ws = (char*)d_ws;
  size_t off = 0;
  auto alloc = [&](size_t bytes) -> char* {
    char* p = ws + off;
    off += (bytes + 255) & ~(size_t)255;
    return p;
  };
  u16* wt_saqkv = (u16*)alloc(768 * 256 * 2);
  u16* wt_saow  = (u16*)alloc(256 * 256 * 2);
  u16* wt_t2iq  = (u16*)alloc(128 * 256 * 2);
  u16* wt_kvq   = (u16*)alloc(384 * 256 * 2);   // t2i_k | t2i_v | i2t_q  ^T
  u16* wt_t2io  = (u16*)alloc(256 * 128 * 2);
  u16* wt_i2tk  = (u16*)alloc(128 * 256 * 2);
  u16* wt_i2tv  = (u16*)alloc(128 * 256 * 2);
  u16* wt_i2to  = (u16*)alloc(256 * 128 * 2);
  u16* wt_w1    = (u16*)alloc(2048 * 256 * 2);
  u16* wt_w2    = (u16*)alloc(256 * 2048 * 2);
  float* b_saqkv = (float*)alloc(768 * 4);
  float* b_kvq   = (float*)alloc(384 * 4);
  float* q1f = (float*)alloc(262144 * 4);
  float* q2f = (float*)alloc(262144 * 4);
  u16* qt    = (u16*)alloc(131072 * 2);
  u16* at2   = (u16*)alloc(131072 * 2);
  u16* o2    = (u16*)alloc(262144 * 2);
  u16* q2b   = (u16*)alloc(262144 * 2);
  u16* hbuf  = (u16*)alloc(2097152 * 2);
  u16* mo    = (u16*)alloc(262144 * 2);
  u16* q3b   = (u16*)alloc(262144 * 2);
  u16* q3pe  = (u16*)alloc(262144 * 2);
  u16* kc    = (u16*)alloc(131072 * 2);
  u16* vc    = (u16*)alloc(131072 * 2);
  u16* ab_big = (u16*)alloc((size_t)16777216 * 2);  // [131072][128] bf16, 32MB

  // --- 1. weight prep ---
  TArgs ta{};
  int nb = 0, id = 0;
  auto addT = [&](const float* s, void* d, int K, int N, int mode) {
    ta.d[id].src = s; ta.d[id].dst = d; ta.d[id].K = K; ta.d[id].N = N;
    ta.d[id].mode = mode; ta.d[id].blk0 = nb;
    nb += (K * N + 255) / 256;
    ++id;
  };
  addT(sa_qw, wt_saqkv, 256, 256, 0);
  addT(sa_kw, wt_saqkv + 256 * 256, 256, 256, 0);
  addT(sa_vw, wt_saqkv + 512 * 256, 256, 256, 0);
  addT(sa_ow, wt_saow, 256, 256, 0);
  addT(t2i_qw, wt_t2iq, 256, 128, 0);
  addT(t2i_kw, wt_kvq, 256, 128, 0);
  addT(t2i_vw, wt_kvq + 128 * 256, 256, 128, 0);
  addT(i2t_qw, wt_kvq + 256 * 256, 256, 128, 0);
  addT(t2i_ow, wt_t2io, 128, 256, 0);
  addT(i2t_kw, wt_i2tk, 256, 128, 0);
  addT(i2t_vw, wt_i2tv, 256, 128, 0);
  addT(i2t_ow, wt_i2to, 128, 256, 0);
  addT(mlp_w1, wt_w1, 256, 2048, 0);
  addT(mlp_w2, wt_w2, 2048, 256, 0);
  addT(sa_qb, b_saqkv, 1, 256, 1);
  addT(sa_kb, b_saqkv + 256, 1, 256, 1);
  addT(sa_vb, b_saqkv + 512, 1, 256, 1);
  addT(t2i_kb, b_kvq, 1, 128, 1);
  addT(t2i_vb, b_kvq + 128, 1, 128, 1);
  addT(i2t_qb, b_kvq + 256, 1, 128, 1);
  ta.n = id;
  k_trans<<<nb, 256, 0, stream>>>(ta);

  // --- 2-7 fused: addpe + QKV + self-attn + saout/ln1/pe + t2i Q proj ---
  k_qphase1<<<32, 256, 0, stream>>>(queries, qpe, wt_saqkv, b_saqkv,
                                    wt_saow, sa_ob, ln1_g, ln1_b,
                                    wt_t2iq, t2i_qb, q1f, qt);
  // --- 8. fused keys projections (r12) ---
  k_gemm_kvq<<<1024, 512, 0, stream>>>(keys, wt_kvq, b_kvq, kvbuf, qb_big);
  // --- 9. t2i attention: split-K partials + merge ---
  k_attn_t2i_part<<<dim3(32, 32), 128, 0, stream>>>(qt, kvbuf, t2i_part);
  k_attn_t2i_merge<<<256, 256, 0, stream>>>(t2i_part, at2);
  // --- 10. t2i out proj ---
  k_gemm<false><<<dim3(2, 8), 256, 0, stream>>>(at2, wt_t2io, t2i_ob,
                                                o2, 256, 128);
  // --- 11. ln2 ---
  k_addln_small<<<256, 256, 0, stream>>>(q1f, o2, ln2_g, ln2_b, q2f, q2b,
                                         nullptr, nullptr);
  // --- 12. MLP ---
  k_gemm<true><<<dim3(16, 8), 256, 0, stream>>>(q2b, wt_w1, mlp_b1,
                                                hbuf, 2048, 256);
  k_gemm<false><<<dim3(2, 8), 256, 0, stream>>>(hbuf, wt_w2, mlp_b2,
                                                mo, 256, 2048);
  // --- 13. ln3 -> f32 queries OUTPUT + bf16 copy + (y+pe) for i2t K ---
  k_addln_small<<<256, 256, 0, stream>>>(q2f, mo, ln3_g, ln3_b, out_q, q3b,
                                         qpe, q3pe);
  // --- 14. i2t small K/V projections ---
  k_gemm<false><<<dim3(1, 8), 256, 0, stream>>>(q3pe, wt_i2tk, i2t_kb,
                                                kc, 128, 256);
  k_gemm<false><<<dim3(1, 8), 256, 0, stream>>>(q3b, wt_i2tv, i2t_vb,
                                                vc, 128, 256);
  // --- 15. i2t attention: qb_big -> ab_big (ws) ---
  k_attn_i2t<<<4096, 256, 0, stream>>>(qb_big, kc, vc, ab_big);
  // --- 16. i2t out proj + keys residual + ln4 -> f32 out_k ---
  k_gemm_ln<<<2048, 256, 0, stream>>>(ab_big, wt_i2to, i2t_ob, keys,
                                      ln4_g, ln4_b, out_k);
}

// Round 17
// 494.227 us; speedup vs baseline: 1.2815x; 1.1147x over previous
//
#include <hip/hip_runtime.h>

typedef unsigned short u16;
typedef __attribute__((ext_vector_type(8))) short s16x8;   // 8 bf16 (4 VGPR)
typedef __attribute__((ext_vector_type(4))) float f32x4;
typedef __attribute__((ext_vector_type(8))) unsigned short u16x8;

__device__ __forceinline__ float b2f(u16 u) {
  union { unsigned int i; float f; } v; v.i = ((unsigned int)u) << 16; return v.f;
}
__device__ __forceinline__ u16 f2b(float f) {
  union { float f; unsigned int i; } v; v.f = f;
  unsigned int r = v.i + 0x7FFFu + ((v.i >> 16) & 1u);   // RNE
  return (u16)(r >> 16);
}
__device__ __forceinline__ int pk2(float a, float b) {
  return (int)f2b(a) | ((int)f2b(b) << 16);
}

// ---------------------------------------------------------------------------
// Fused queries phase 1 (per batch, 32 blocks x 256 threads):
//   q0 = queries+pe -> QKV proj -> self-attn -> sa-out + ln1 (+pe) ->
//   t2i Q proj. All intermediates in LDS; weights direct from L2.
// Outputs: q1f f32 [1024][256] (ln2 residual), qt bf16 [1024][128].
// (r16-verbatim, proven -23 us.)
// ---------------------------------------------------------------------------
__global__ void __launch_bounds__(256) k_qphase1(
    const float* __restrict__ queries, const float* __restrict__ qpe,
    const u16* __restrict__ Wqkv,   // [768][256] bf16
    const float* __restrict__ bqkv, // [768]
    const u16* __restrict__ Wo,     // [256][256] bf16
    const float* __restrict__ ob,   // [256]
    const float* __restrict__ g1, const float* __restrict__ b1,
    const u16* __restrict__ Wq2,    // [128][256] bf16
    const float* __restrict__ qb2,  // [128]
    float* __restrict__ q1f, u16* __restrict__ qt)
{
  __shared__ float q0f[32][260];      // ~33 KB
  __shared__ u16 qkv[32][776];        // ~48.5 KB
  __shared__ u16 atb[32][264];        // ~16.5 KB
  __shared__ float rs[32][4], rq[32][4];
  const int b = blockIdx.x;
  const int t = threadIdx.x;
  const int lane = t & 63, w = t >> 6;
  const int l16 = lane & 15, lhi = lane >> 4;

  {
    const float4* qg = (const float4*)(queries + (size_t)b * 8192);
    const float4* pg = (const float4*)(qpe + (size_t)b * 8192);
    for (int i = t; i < 2048; i += 256) {
      int row = i >> 6, c4 = (i & 63) * 4;
      float4 qv = qg[i], pv = pg[i];
      *(float4*)&q0f[row][c4] =
          (float4){qv.x + pv.x, qv.y + pv.y, qv.z + pv.z, qv.w + pv.w};
    }
  }
  __syncthreads();

  {
    f32x4 acc[2][12];
#pragma unroll
    for (int i = 0; i < 2; ++i)
#pragma unroll
      for (int j = 0; j < 12; ++j) acc[i][j] = (f32x4){0.f, 0.f, 0.f, 0.f};
#pragma unroll
    for (int kk = 0; kk < 8; ++kk) {
      const int ko = kk * 32 + lhi * 8;
      s16x8 af[2], bfr[12];
#pragma unroll
      for (int mt = 0; mt < 2; ++mt) {
        const float* ap = &q0f[mt * 16 + l16][ko];
        float4 x = *(const float4*)ap;
        float4 y = *(const float4*)(ap + 4);
        int4 p = (int4){pk2(x.x, x.y), pk2(x.z, x.w),
                        pk2(y.x, y.y), pk2(y.z, y.w)};
        af[mt] = *(s16x8*)&p;
      }
#pragma unroll
      for (int nt = 0; nt < 12; ++nt) {
        int row = w * 192 + nt * 16 + l16;
        bfr[nt] = *(const s16x8*)(Wqkv + (size_t)row * 256 + ko);
      }
#pragma unroll
      for (int mt = 0; mt < 2; ++mt)
#pragma unroll
        for (int nt = 0; nt < 12; ++nt)
          acc[mt][nt] = __builtin_amdgcn_mfma_f32_16x16x32_bf16(
              af[mt], bfr[nt], acc[mt][nt], 0, 0, 0);
    }
#pragma unroll
    for (int mt = 0; mt < 2; ++mt)
#pragma unroll
      for (int nt = 0; nt < 12; ++nt) {
        int cg = w * 192 + nt * 16 + l16;
        float bv = bqkv[cg];
#pragma unroll
        for (int rg = 0; rg < 4; ++rg)
          qkv[mt * 16 + lhi * 4 + rg][cg] = f2b(acc[mt][nt][rg] + bv);
      }
  }
  __syncthreads();

  {
    int q = t >> 3, h = t & 7;
    float Qh[32];
#pragma unroll
    for (int c = 0; c < 4; ++c) {
      u16x8 v = *(const u16x8*)&qkv[q][h * 32 + c * 8];
#pragma unroll
      for (int e = 0; e < 8; ++e) Qh[c * 8 + e] = b2f(v[e]);
    }
    float s[32], mx = -INFINITY;
#pragma unroll 4
    for (int j = 0; j < 32; ++j) {
      float a = 0.f;
#pragma unroll
      for (int c = 0; c < 4; ++c) {
        u16x8 v = *(const u16x8*)&qkv[j][256 + h * 32 + c * 8];
#pragma unroll
        for (int e = 0; e < 8; ++e) a += Qh[c * 8 + e] * b2f(v[e]);
      }
      s[j] = a * 0.17677669529663687f;
      mx = fmaxf(mx, s[j]);
    }
    float sum = 0.f;
#pragma unroll
    for (int j = 0; j < 32; ++j) { s[j] = __expf(s[j] - mx); sum += s[j]; }
    float o[32];
#pragma unroll
    for (int d = 0; d < 32; ++d) o[d] = 0.f;
#pragma unroll 4
    for (int j = 0; j < 32; ++j) {
      float p = s[j];
#pragma unroll
      for (int c = 0; c < 4; ++c) {
        u16x8 v = *(const u16x8*)&qkv[j][512 + h * 32 + c * 8];
#pragma unroll
        for (int e = 0; e < 8; ++e) o[c * 8 + e] += p * b2f(v[e]);
      }
    }
    float inv = 1.f / sum;
#pragma unroll
    for (int d = 0; d < 32; ++d) atb[q][h * 32 + d] = f2b(o[d] * inv);
  }
  __syncthreads();

  float yv[2][4][4];
  {
    f32x4 acc[2][4];
#pragma unroll
    for (int i = 0; i < 2; ++i)
#pragma unroll
      for (int j = 0; j < 4; ++j) acc[i][j] = (f32x4){0.f, 0.f, 0.f, 0.f};
#pragma unroll
    for (int kk = 0; kk < 8; ++kk) {
      const int ko = kk * 32 + lhi * 8;
      s16x8 af[2], bfr[4];
#pragma unroll
      for (int mt = 0; mt < 2; ++mt)
        af[mt] = *(const s16x8*)&atb[mt * 16 + l16][ko];
#pragma unroll
      for (int nt = 0; nt < 4; ++nt) {
        int row = w * 64 + nt * 16 + l16;
        bfr[nt] = *(const s16x8*)(Wo + (size_t)row * 256 + ko);
      }
#pragma unroll
      for (int mt = 0; mt < 2; ++mt)
#pragma unroll
        for (int nt = 0; nt < 4; ++nt)
          acc[mt][nt] = __builtin_amdgcn_mfma_f32_16x16x32_bf16(
              af[mt], bfr[nt], acc[mt][nt], 0, 0, 0);
    }
#pragma unroll
    for (int mt = 0; mt < 2; ++mt) {
#pragma unroll
      for (int rg = 0; rg < 4; ++rg) {
        int row = mt * 16 + lhi * 4 + rg;
        float ps = 0.f, pq = 0.f;
#pragma unroll
        for (int nt = 0; nt < 4; ++nt) {
          int cg = w * 64 + nt * 16 + l16;
          float v = acc[mt][nt][rg] + ob[cg] + q0f[row][cg];
          yv[mt][nt][rg] = v;
          ps += v; pq += v * v;
        }
#pragma unroll
        for (int msk = 1; msk < 16; msk <<= 1) {
          ps += __shfl_xor(ps, msk);
          pq += __shfl_xor(pq, msk);
        }
        if (l16 == 0) { rs[row][w] = ps; rq[row][w] = pq; }
      }
    }
  }
  __syncthreads();
  {
#pragma unroll
    for (int mt = 0; mt < 2; ++mt) {
#pragma unroll
      for (int rg = 0; rg < 4; ++rg) {
        int row = mt * 16 + lhi * 4 + rg;
        float ts = rs[row][0] + rs[row][1] + rs[row][2] + rs[row][3];
        float tq = rq[row][0] + rq[row][1] + rq[row][2] + rq[row][3];
        float mean = ts * (1.f / 256.f);
        float var = tq * (1.f / 256.f) - mean * mean;
        float rstd = rsqrtf(var + 1e-5f);
#pragma unroll
        for (int nt = 0; nt < 4; ++nt) {
          int cg = w * 64 + nt * 16 + l16;
          float y = (yv[mt][nt][rg] - mean) * rstd * g1[cg] + b1[cg];
          size_t gi = ((size_t)b * 32 + row) * 256 + cg;
          q1f[gi] = y;
          atb[row][cg] = f2b(y + qpe[gi]);
        }
      }
    }
  }
  __syncthreads();

  {
    f32x4 acc[2][2];
#pragma unroll
    for (int i = 0; i < 2; ++i)
#pragma unroll
      for (int j = 0; j < 2; ++j) acc[i][j] = (f32x4){0.f, 0.f, 0.f, 0.f};
#pragma unroll
    for (int kk = 0; kk < 8; ++kk) {
      const int ko = kk * 32 + lhi * 8;
      s16x8 af[2], bfr[2];
#pragma unroll
      for (int mt = 0; mt < 2; ++mt)
        af[mt] = *(const s16x8*)&atb[mt * 16 + l16][ko];
#pragma unroll
      for (int nt = 0; nt < 2; ++nt) {
        int row = w * 32 + nt * 16 + l16;
        bfr[nt] = *(const s16x8*)(Wq2 + (size_t)row * 256 + ko);
      }
#pragma unroll
      for (int mt = 0; mt < 2; ++mt)
#pragma unroll
        for (int nt = 0; nt < 2; ++nt)
          acc[mt][nt] = __builtin_amdgcn_mfma_f32_16x16x32_bf16(
              af[mt], bfr[nt], acc[mt][nt], 0, 0, 0);
    }
#pragma unroll
    for (int mt = 0; mt < 2; ++mt)
#pragma unroll
      for (int nt = 0; nt < 2; ++nt) {
        int cg = w * 32 + nt * 16 + l16;
        float bv = qb2[cg];
#pragma unroll
        for (int rg = 0; rg < 4; ++rg) {
          int row = mt * 16 + lhi * 4 + rg;
          qt[((size_t)b * 32 + row) * 128 + cg] = f2b(acc[mt][nt][rg] + bv);
        }
      }
  }
}

// ---------------------------------------------------------------------------
// Fused queries phase 2 (per batch, 32 blocks x 256 threads):
//   t2i out-proj + ln2 -> MLP(relu, hidden streamed in 4x512 chunks) + ln3
//   -> out_q(f32) + i2t K proj (on y+pe) + i2t V proj (on y).
// All intermediates LDS-resident; weights direct from L2.
// ---------------------------------------------------------------------------
__global__ void __launch_bounds__(256) k_qphase2(
    const u16* __restrict__ at2,   // [1024][128] bf16
    const float* __restrict__ q1f, // [1024][256] f32 (ln2 residual)
    const u16* __restrict__ Wo2,   // [256][128] bf16 (t2i_ow^T)
    const float* __restrict__ ob2, // [256]
    const float* __restrict__ g2, const float* __restrict__ b2v,
    const u16* __restrict__ W1,    // [2048][256] bf16 (mlp_w1^T)
    const float* __restrict__ bb1, // [2048]
    const u16* __restrict__ W2,    // [256][2048] bf16 (mlp_w2^T)
    const float* __restrict__ bb2, // [256]
    const float* __restrict__ g3, const float* __restrict__ b3v,
    const float* __restrict__ qpe,
    const u16* __restrict__ Wk,    // [128][256] bf16 (i2t_kw^T)
    const float* __restrict__ kb,  // [128]
    const u16* __restrict__ Wv,    // [128][256] bf16 (i2t_vw^T)
    const float* __restrict__ vbv, // [128]
    float* __restrict__ out_q, u16* __restrict__ kc, u16* __restrict__ vc)
{
  __shared__ u16 atb[32][136];        // 8.7 KB (t2i attn out)
  __shared__ float q2f[32][260];      // 33 KB  (ln2 out f32, ln3 residual)
  __shared__ u16 q2b[32][264];        // 17 KB  (ln2 out bf16, MLP input)
  __shared__ u16 hb[32][520];         // 33 KB  (hidden chunk)
  __shared__ u16 yb[32][264];         // 17 KB  (ln3 out bf16)
  __shared__ u16 ypeb[32][264];       // 17 KB  (ln3 out + pe)
  __shared__ float rs[32][4], rq[32][4];
  const int b = blockIdx.x;
  const int t = threadIdx.x;
  const int lane = t & 63, w = t >> 6;
  const int l16 = lane & 15, lhi = lane >> 4;

  // stage A: load at2 rows
  {
    const int4* src = (const int4*)(at2 + (size_t)b * 32 * 128);
    for (int i = t; i < 512; i += 256) {
      int r = i >> 4, c8 = i & 15;
      *(int4*)&atb[r][c8 * 8] = src[i];
    }
  }
  __syncthreads();

  // stage B: t2i out proj + residual(q1f) + ln2 -> q2f/q2b
  {
    f32x4 acc[2][4];
#pragma unroll
    for (int i = 0; i < 2; ++i)
#pragma unroll
      for (int j = 0; j < 4; ++j) acc[i][j] = (f32x4){0.f, 0.f, 0.f, 0.f};
#pragma unroll
    for (int kk = 0; kk < 4; ++kk) {       // K = 128
      const int ko = kk * 32 + lhi * 8;
      s16x8 af[2], bfr[4];
#pragma unroll
      for (int mt = 0; mt < 2; ++mt)
        af[mt] = *(const s16x8*)&atb[mt * 16 + l16][ko];
#pragma unroll
      for (int nt = 0; nt < 4; ++nt) {
        int row = w * 64 + nt * 16 + l16;
        bfr[nt] = *(const s16x8*)(Wo2 + (size_t)row * 128 + ko);
      }
#pragma unroll
      for (int mt = 0; mt < 2; ++mt)
#pragma unroll
        for (int nt = 0; nt < 4; ++nt)
          acc[mt][nt] = __builtin_amdgcn_mfma_f32_16x16x32_bf16(
              af[mt], bfr[nt], acc[mt][nt], 0, 0, 0);
    }
    float yv[2][4][4];
#pragma unroll
    for (int mt = 0; mt < 2; ++mt) {
#pragma unroll
      for (int rg = 0; rg < 4; ++rg) {
        int row = mt * 16 + lhi * 4 + rg;
        float ps = 0.f, pq = 0.f;
#pragma unroll
        for (int nt = 0; nt < 4; ++nt) {
          int cg = w * 64 + nt * 16 + l16;
          float v = acc[mt][nt][rg] + ob2[cg] +
                    q1f[((size_t)b * 32 + row) * 256 + cg];
          yv[mt][nt][rg] = v;
          ps += v; pq += v * v;
        }
#pragma unroll
        for (int msk = 1; msk < 16; msk <<= 1) {
          ps += __shfl_xor(ps, msk);
          pq += __shfl_xor(pq, msk);
        }
        if (l16 == 0) { rs[row][w] = ps; rq[row][w] = pq; }
      }
    }
    __syncthreads();
#pragma unroll
    for (int mt = 0; mt < 2; ++mt) {
#pragma unroll
      for (int rg = 0; rg < 4; ++rg) {
        int row = mt * 16 + lhi * 4 + rg;
        float ts = rs[row][0] + rs[row][1] + rs[row][2] + rs[row][3];
        float tq = rq[row][0] + rq[row][1] + rq[row][2] + rq[row][3];
        float mean = ts * (1.f / 256.f);
        float var = tq * (1.f / 256.f) - mean * mean;
        float rstd = rsqrtf(var + 1e-5f);
#pragma unroll
        for (int nt = 0; nt < 4; ++nt) {
          int cg = w * 64 + nt * 16 + l16;
          float y = (yv[mt][nt][rg] - mean) * rstd * g2[cg] + b2v[cg];
          q2f[row][cg] = y;
          q2b[row][cg] = f2b(y);
        }
      }
    }
  }
  __syncthreads();

  // stage C: MLP, hidden streamed in 4 chunks of 512
  f32x4 oacc[2][4];
#pragma unroll
  for (int i = 0; i < 2; ++i)
#pragma unroll
    for (int j = 0; j < 4; ++j) oacc[i][j] = (f32x4){0.f, 0.f, 0.f, 0.f};
  for (int hc = 0; hc < 4; ++hc) {
    f32x4 a1[2][8];
#pragma unroll
    for (int i = 0; i < 2; ++i)
#pragma unroll
      for (int j = 0; j < 8; ++j) a1[i][j] = (f32x4){0.f, 0.f, 0.f, 0.f};
#pragma unroll
    for (int kk = 0; kk < 8; ++kk) {       // K = 256
      const int ko = kk * 32 + lhi * 8;
      s16x8 af[2], bfr[8];
#pragma unroll
      for (int mt = 0; mt < 2; ++mt)
        af[mt] = *(const s16x8*)&q2b[mt * 16 + l16][ko];
#pragma unroll
      for (int nt = 0; nt < 8; ++nt) {
        int row = hc * 512 + w * 128 + nt * 16 + l16;
        bfr[nt] = *(const s16x8*)(W1 + (size_t)row * 256 + ko);
      }
#pragma unroll
      for (int mt = 0; mt < 2; ++mt)
#pragma unroll
        for (int nt = 0; nt < 8; ++nt)
          a1[mt][nt] = __builtin_amdgcn_mfma_f32_16x16x32_bf16(
              af[mt], bfr[nt], a1[mt][nt], 0, 0, 0);
    }
    if (hc) __syncthreads();               // prev GEMM2 done reading hb
#pragma unroll
    for (int mt = 0; mt < 2; ++mt)
#pragma unroll
      for (int nt = 0; nt < 8; ++nt) {
        int cg = w * 128 + nt * 16 + l16;
        float bv = bb1[hc * 512 + cg];
#pragma unroll
        for (int rg = 0; rg < 4; ++rg)
          hb[mt * 16 + lhi * 4 + rg][cg] =
              f2b(fmaxf(a1[mt][nt][rg] + bv, 0.f));
      }
    __syncthreads();
#pragma unroll
    for (int kk2 = 0; kk2 < 16; ++kk2) {   // chunk K = 512
      const int ko = kk2 * 32 + lhi * 8;
      s16x8 af[2], bfr[4];
#pragma unroll
      for (int mt = 0; mt < 2; ++mt)
        af[mt] = *(const s16x8*)&hb[mt * 16 + l16][ko];
#pragma unroll
      for (int nt = 0; nt < 4; ++nt) {
        int row = w * 64 + nt * 16 + l16;
        bfr[nt] = *(const s16x8*)(W2 + (size_t)row * 2048 + hc * 512 + ko);
      }
#pragma unroll
      for (int mt = 0; mt < 2; ++mt)
#pragma unroll
        for (int nt = 0; nt < 4; ++nt)
          oacc[mt][nt] = __builtin_amdgcn_mfma_f32_16x16x32_bf16(
              af[mt], bfr[nt], oacc[mt][nt], 0, 0, 0);
    }
  }

  // stage D: + bb2 + q2f residual -> ln3 -> out_q f32, yb, ypeb
  {
    float yv[2][4][4];
#pragma unroll
    for (int mt = 0; mt < 2; ++mt) {
#pragma unroll
      for (int rg = 0; rg < 4; ++rg) {
        int row = mt * 16 + lhi * 4 + rg;
        float ps = 0.f, pq = 0.f;
#pragma unroll
        for (int nt = 0; nt < 4; ++nt) {
          int cg = w * 64 + nt * 16 + l16;
          float v = oacc[mt][nt][rg] + bb2[cg] + q2f[row][cg];
          yv[mt][nt][rg] = v;
          ps += v; pq += v * v;
        }
#pragma unroll
        for (int msk = 1; msk < 16; msk <<= 1) {
          ps += __shfl_xor(ps, msk);
          pq += __shfl_xor(pq, msk);
        }
        if (l16 == 0) { rs[row][w] = ps; rq[row][w] = pq; }
      }
    }
    __syncthreads();
#pragma unroll
    for (int mt = 0; mt < 2; ++mt) {
#pragma unroll
      for (int rg = 0; rg < 4; ++rg) {
        int row = mt * 16 + lhi * 4 + rg;
        float ts = rs[row][0] + rs[row][1] + rs[row][2] + rs[row][3];
        float tq = rq[row][0] + rq[row][1] + rq[row][2] + rq[row][3];
        float mean = ts * (1.f / 256.f);
        float var = tq * (1.f / 256.f) - mean * mean;
        float rstd = rsqrtf(var + 1e-5f);
#pragma unroll
        for (int nt = 0; nt < 4; ++nt) {
          int cg = w * 64 + nt * 16 + l16;
          float y = (yv[mt][nt][rg] - mean) * rstd * g3[cg] + b3v[cg];
          size_t gi = ((size_t)b * 32 + row) * 256 + cg;
          out_q[gi] = y;
          yb[row][cg] = f2b(y);
          ypeb[row][cg] = f2b(y + qpe[gi]);
        }
      }
    }
  }
  __syncthreads();

  // stage E: kc = ypeb @ Wk + kb; vc = yb @ Wv + vbv  (N=128, K=256)
  {
    f32x4 ak[2][2], av[2][2];
#pragma unroll
    for (int i = 0; i < 2; ++i)
#pragma unroll
      for (int j = 0; j < 2; ++j) {
        ak[i][j] = (f32x4){0.f, 0.f, 0.f, 0.f};
        av[i][j] = (f32x4){0.f, 0.f, 0.f, 0.f};
      }
#pragma unroll
    for (int kk = 0; kk < 8; ++kk) {
      const int ko = kk * 32 + lhi * 8;
      s16x8 afk[2], afv[2], bk[2], bv2[2];
#pragma unroll
      for (int mt = 0; mt < 2; ++mt) {
        afk[mt] = *(const s16x8*)&ypeb[mt * 16 + l16][ko];
        afv[mt] = *(const s16x8*)&yb[mt * 16 + l16][ko];
      }
#pragma unroll
      for (int nt = 0; nt < 2; ++nt) {
        int row = w * 32 + nt * 16 + l16;
        bk[nt] = *(const s16x8*)(Wk + (size_t)row * 256 + ko);
        bv2[nt] = *(const s16x8*)(Wv + (size_t)row * 256 + ko);
      }
#pragma unroll
      for (int mt = 0; mt < 2; ++mt)
#pragma unroll
        for (int nt = 0; nt < 2; ++nt) {
          ak[mt][nt] = __builtin_amdgcn_mfma_f32_16x16x32_bf16(
              afk[mt], bk[nt], ak[mt][nt], 0, 0, 0);
          av[mt][nt] = __builtin_amdgcn_mfma_f32_16x16x32_bf16(
              afv[mt], bv2[nt], av[mt][nt], 0, 0, 0);
        }
    }
#pragma unroll
    for (int mt = 0; mt < 2; ++mt)
#pragma unroll
      for (int nt = 0; nt < 2; ++nt) {
        int cg = w * 32 + nt * 16 + l16;
        float kbv = kb[cg], vbb = vbv[cg];
#pragma unroll
        for (int rg = 0; rg < 4; ++rg) {
          int row = mt * 16 + lhi * 4 + rg;
          size_t gi = ((size_t)b * 32 + row) * 128 + cg;
          kc[gi] = f2b(ak[mt][nt][rg] + kbv);
          vc[gi] = f2b(av[mt][nt][rg] + vbb);
        }
      }
  }
}

// ---------------------------------------------------------------------------
// Fused keys projections (r12-verbatim, 123 us): A staged in LDS, W direct.
// ---------------------------------------------------------------------------
__global__ void __launch_bounds__(512, 2) k_gemm_kvq(
    const float* __restrict__ A, const u16* __restrict__ Wt,
    const float* __restrict__ bias, u16* __restrict__ KV, u16* __restrict__ QB)
{
  __shared__ char smem[49152];             // GEMM: A 16KB; epilogue: ldsO 48KB
  char* AsB = smem;
  const int t = threadIdx.x;
  const int lane = t & 63, wid = t >> 6;
  const int wm = wid >> 2, wn = wid & 3;   // 2 x 4 waves
  const int l16 = lane & 15, lhi = lane >> 4;
  const int bRow = blockIdx.x * 128;

  f32x4 acc[4][6];
#pragma unroll
  for (int i = 0; i < 4; ++i)
#pragma unroll
    for (int j = 0; j < 6; ++j) acc[i][j] = (f32x4){0.f, 0.f, 0.f, 0.f};

  for (int kt = 0; kt < 4; ++kt) {
    const int k0 = kt << 6;
    float4 a0r[2], a1r[2];
#pragma unroll
    for (int i = 0; i < 2; ++i) {
      int L = i * 8192 + t * 16;
      int r = L >> 7, cl = (L >> 4) & 7;
      const float* Af = A + (size_t)(bRow + r) * 256 + k0 + cl * 8;
      a0r[i] = *(const float4*)Af;
      a1r[i] = *(const float4*)(Af + 4);
    }
    if (kt) __syncthreads();
#pragma unroll
    for (int i = 0; i < 2; ++i) {
      int L = i * 8192 + t * 16;
      int r = L >> 7, cl = (L >> 4) & 7;
      int4 p = (int4){pk2(a0r[i].x, a0r[i].y), pk2(a0r[i].z, a0r[i].w),
                      pk2(a1r[i].x, a1r[i].y), pk2(a1r[i].z, a1r[i].w)};
      *(int4*)(AsB + r * 128 + ((cl ^ (r & 7)) << 4)) = p;
    }
    __syncthreads();
#pragma unroll
    for (int kk = 0; kk < 2; ++kk) {
      s16x8 af[4], bfr[6];
#pragma unroll
      for (int nt = 0; nt < 6; ++nt) {
        int row = wn * 96 + nt * 16 + l16;
        bfr[nt] = *(const s16x8*)(Wt + (size_t)row * 256 + k0 + kk * 32 + lhi * 8);
      }
#pragma unroll
      for (int mt = 0; mt < 4; ++mt) {
        int r = wm * 64 + mt * 16 + l16;
        int ch = kk * 4 + lhi;
        af[mt] = *(const s16x8*)(AsB + r * 128 + ((ch ^ (r & 7)) << 4));
      }
#pragma unroll
      for (int mt = 0; mt < 4; ++mt)
#pragma unroll
        for (int nt = 0; nt < 6; ++nt)
          acc[mt][nt] = __builtin_amdgcn_mfma_f32_16x16x32_bf16(
              af[mt], bfr[nt], acc[mt][nt], 0, 0, 0);
    }
  }
  u16* ldsO = (u16*)smem;                  // [64][384] u16 = 48KB
  for (int half = 0; half < 2; ++half) {
    __syncthreads();
    if (wm == half) {
#pragma unroll
      for (int mt = 0; mt < 4; ++mt) {
#pragma unroll
        for (int nt = 0; nt < 6; ++nt) {
          int cg = wn * 96 + nt * 16 + l16;
          float bv = bias[cg];
#pragma unroll
          for (int rg = 0; rg < 4; ++rg) {
            int r = mt * 16 + lhi * 4 + rg;
            ldsO[r * 384 + cg] = f2b(acc[mt][nt][rg] + bv);
          }
        }
      }
    }
    __syncthreads();
#pragma unroll
    for (int i = 0; i < 6; ++i) {
      int chunk = i * 512 + t;
      int r = chunk / 48, c8 = chunk - r * 48;
      int row = bRow + half * 64 + r;
      int4 v = *(int4*)(ldsO + r * 384 + c8 * 8);
      if (c8 < 32) *(int4*)(KV + (size_t)row * 256 + c8 * 8) = v;
      else         *(int4*)(QB + (size_t)row * 128 + (c8 - 32) * 8) = v;
    }
  }
}

// ---------------------------------------------------------------------------
// i2t out-proj + residual + LN4 (r12-verbatim). BM=64, W direct, grid M/64.
// ---------------------------------------------------------------------------
__global__ void __launch_bounds__(256) k_gemm_ln(
    const u16* __restrict__ A, const u16* __restrict__ Wt,
    const float* __restrict__ bias, const float* __restrict__ res,
    const float* __restrict__ g, const float* __restrict__ bl,
    float* __restrict__ out)
{
  __shared__ int4 smem4[512];              // 8 KB A-tile
  __shared__ float rsum[2][32][2], rsq[2][32][2];
  char* AsB = (char*)smem4;
  const int t = threadIdx.x;
  const int lane = t & 63, wid = t >> 6;
  const int wm = wid >> 1, wn = wid & 1;
  const int l16 = lane & 15, lhi = lane >> 4;
  const int bRow = blockIdx.x * 64;

  f32x4 acc[2][8];
#pragma unroll
  for (int i = 0; i < 2; ++i)
#pragma unroll
    for (int j = 0; j < 8; ++j) acc[i][j] = (f32x4){0.f, 0.f, 0.f, 0.f};

  for (int kt = 0; kt < 2; ++kt) {
    const int k0 = kt << 6;
    int4 av[2];
#pragma unroll
    for (int i = 0; i < 2; ++i) {          // A: 64 x 64
      int L = i * 4096 + t * 16;
      int r = L >> 7, cl = (L >> 4) & 7;
      av[i] = *(const int4*)(A + (size_t)(bRow + r) * 128 + k0 + cl * 8);
    }
    if (kt) __syncthreads();
#pragma unroll
    for (int i = 0; i < 2; ++i) {
      int L = i * 4096 + t * 16;
      int r = L >> 7, cl = (L >> 4) & 7;
      *(int4*)(AsB + r * 128 + ((cl ^ (r & 7)) << 4)) = av[i];
    }
    __syncthreads();
#pragma unroll
    for (int kk = 0; kk < 2; ++kk) {
      s16x8 af[2], bfr[8];
#pragma unroll
      for (int nt = 0; nt < 8; ++nt) {
        int row = wn * 128 + nt * 16 + l16;
        bfr[nt] = *(const s16x8*)(Wt + (size_t)row * 128 + k0 + kk * 32 + lhi * 8);
      }
#pragma unroll
      for (int mt = 0; mt < 2; ++mt) {
        int r = wm * 32 + mt * 16 + l16;
        int ch = kk * 4 + lhi;
        af[mt] = *(const s16x8*)(AsB + r * 128 + ((ch ^ (r & 7)) << 4));
      }
#pragma unroll
      for (int mt = 0; mt < 2; ++mt)
#pragma unroll
        for (int nt = 0; nt < 8; ++nt)
          acc[mt][nt] = __builtin_amdgcn_mfma_f32_16x16x32_bf16(
              af[mt], bfr[nt], acc[mt][nt], 0, 0, 0);
    }
  }
#pragma unroll
  for (int mt = 0; mt < 2; ++mt) {
#pragma unroll
    for (int nt = 0; nt < 8; ++nt) {
      int cg = wn * 128 + nt * 16 + l16;
      float bv = bias[cg];
#pragma unroll
      for (int rg = 0; rg < 4; ++rg) {
        int row = bRow + wm * 32 + mt * 16 + lhi * 4 + rg;
        acc[mt][nt][rg] += bv + res[(size_t)row * 256 + cg];
      }
    }
  }
#pragma unroll
  for (int mt = 0; mt < 2; ++mt) {
#pragma unroll
    for (int rg = 0; rg < 4; ++rg) {
      float ps = 0.f, pq = 0.f;
#pragma unroll
      for (int nt = 0; nt < 8; ++nt) {
        float v = acc[mt][nt][rg];
        ps += v; pq += v * v;
      }
#pragma unroll
      for (int msk = 1; msk < 16; msk <<= 1) {
        ps += __shfl_xor(ps, msk);
        pq += __shfl_xor(pq, msk);
      }
      if (l16 == 0) {
        int rl = mt * 16 + lhi * 4 + rg;
        rsum[wm][rl][wn] = ps;
        rsq[wm][rl][wn] = pq;
      }
    }
  }
  __syncthreads();
#pragma unroll
  for (int mt = 0; mt < 2; ++mt) {
#pragma unroll
    for (int rg = 0; rg < 4; ++rg) {
      int rl = mt * 16 + lhi * 4 + rg;
      float ts = rsum[wm][rl][0] + rsum[wm][rl][1];
      float tq = rsq[wm][rl][0] + rsq[wm][rl][1];
      float mean = ts * (1.f / 256.f);
      float var = tq * (1.f / 256.f) - mean * mean;
      float rstd = rsqrtf(var + 1e-5f);
      int row = bRow + wm * 32 + rl;
#pragma unroll
      for (int nt = 0; nt < 8; ++nt) {
        int cg = wn * 128 + nt * 16 + l16;
        out[(size_t)row * 256 + cg] =
            (acc[mt][nt][rg] - mean) * rstd * g[cg] + bl[cg];
      }
    }
  }
}

// ---------------------------------------------------------------------------
struct TDesc { const float* src; void* dst; int K; int N; int mode; int blk0; };
struct TArgs { TDesc d[24]; int n; };

__global__ void __launch_bounds__(256) k_trans(TArgs a)
{
  int blk = blockIdx.x;
  int i = 0;
  while (i + 1 < a.n && blk >= a.d[i + 1].blk0) ++i;
  TDesc td = a.d[i];
  int e = (blk - td.blk0) * 256 + threadIdx.x;
  int tot = td.K * td.N;
  if (e >= tot) return;
  if (td.mode == 0) {
    int k = e / td.N, n = e - k * td.N;
    ((u16*)td.dst)[(size_t)n * td.K + k] = f2b(td.src[e]);
  } else {
    ((float*)td.dst)[e] = td.src[e];
  }
}

// ---------------------------------------------------------------------------
// t2i partial attention (split-K flash). Grid (32 chunks, 32 b), 128 threads.
// ---------------------------------------------------------------------------
__global__ void __launch_bounds__(128) k_attn_t2i_part(
    const u16* __restrict__ Qt, const u16* __restrict__ KV,
    float* __restrict__ part)
{
  __shared__ int4 kvs[4096];               // 64 KB = 128 rows x 256 u16
  int c = blockIdx.x, b = blockIdx.y;
  int tid = threadIdx.x;
  const int4* src = (const int4*)(KV + ((size_t)b * 4096 + c * 128) * 256);
  for (int i = tid; i < 4096; i += 128) kvs[i] = src[i];
  __syncthreads();
  int qp = tid >> 3, h = tid & 7;
  const u16* lds = (const u16*)kvs;

  float q0[16], q1[16];
  {
    const u16* p0 = Qt + (size_t)(b * 32 + qp) * 128 + h * 16;
    const u16* p1 = Qt + (size_t)(b * 32 + qp + 16) * 128 + h * 16;
    u16x8 a0 = *(const u16x8*)p0, b0 = *(const u16x8*)(p0 + 8);
    u16x8 a1 = *(const u16x8*)p1, b1 = *(const u16x8*)(p1 + 8);
#pragma unroll
    for (int e = 0; e < 8; ++e) {
      q0[e] = b2f(a0[e]); q0[8 + e] = b2f(b0[e]);
      q1[e] = b2f(a1[e]); q1[8 + e] = b2f(b1[e]);
    }
  }
  float m0 = -INFINITY, s0 = 0.f, m1 = -INFINITY, s1 = 0.f;
  float acc0[16], acc1[16];
#pragma unroll
  for (int d = 0; d < 16; ++d) { acc0[d] = 0.f; acc1[d] = 0.f; }

  for (int j = 0; j < 128; ++j) {
    const u16* kr = lds + j * 256 + h * 16;
    u16x8 ka = *(const u16x8*)kr;
    u16x8 kb = *(const u16x8*)(kr + 8);
    float l0 = 0.f, l1 = 0.f;
#pragma unroll
    for (int e = 0; e < 8; ++e) {
      float klo = b2f(ka[e]), khi = b2f(kb[e]);
      l0 += q0[e] * klo + q0[8 + e] * khi;
      l1 += q1[e] * klo + q1[8 + e] * khi;
    }
    l0 *= 0.25f; l1 *= 0.25f;
    const u16* vr = kr + 128;
    u16x8 va = *(const u16x8*)vr;
    u16x8 vb = *(const u16x8*)(vr + 8);
    float nm0 = fmaxf(m0, l0), nm1 = fmaxf(m1, l1);
    float c0 = __expf(m0 - nm0), p0 = __expf(l0 - nm0);
    float c1 = __expf(m1 - nm1), p1 = __expf(l1 - nm1);
    s0 = s0 * c0 + p0; s1 = s1 * c1 + p1;
#pragma unroll
    for (int e = 0; e < 8; ++e) {
      float vlo = b2f(va[e]), vhi = b2f(vb[e]);
      acc0[e] = acc0[e] * c0 + p0 * vlo;
      acc0[8 + e] = acc0[8 + e] * c0 + p0 * vhi;
      acc1[e] = acc1[e] * c1 + p1 * vlo;
      acc1[8 + e] = acc1[8 + e] * c1 + p1 * vhi;
    }
    m0 = nm0; m1 = nm1;
  }
  float* r0 = part + (((size_t)(b * 32 + qp) * 8 + h) * 32 + c) * 18;
  float* r1 = part + (((size_t)(b * 32 + qp + 16) * 8 + h) * 32 + c) * 18;
#pragma unroll
  for (int d = 0; d < 16; ++d) { r0[d] = acc0[d]; r1[d] = acc1[d]; }
  r0[16] = m0; r0[17] = s0;
  r1[16] = m1; r1[17] = s1;
}

// ---------------------------------------------------------------------------
__global__ void __launch_bounds__(256) k_attn_t2i_merge(
    const float* __restrict__ part, u16* __restrict__ out)
{
  int b = blockIdx.x >> 3, h = blockIdx.x & 7;
  int q = threadIdx.x >> 3, ds = threadIdx.x & 7;
  const float* base = part + (((size_t)(b * 32 + q) * 8 + h) * 32) * 18;
  float mg = -INFINITY;
#pragma unroll 4
  for (int c = 0; c < 32; ++c) mg = fmaxf(mg, base[c * 18 + 16]);
  float sg = 0.f, a0 = 0.f, a1 = 0.f;
#pragma unroll 4
  for (int c = 0; c < 32; ++c) {
    const float* rec = base + c * 18;
    float w = __expf(rec[16] - mg);
    sg += rec[17] * w;
    a0 += rec[ds * 2] * w;
    a1 += rec[ds * 2 + 1] * w;
  }
  float inv = 1.f / sg;
  u16* op = out + (size_t)(b * 32 + q) * 128 + h * 16 + ds * 2;
  op[0] = f2b(a0 * inv);
  op[1] = f2b(a1 * inv);
}

// ---------------------------------------------------------------------------
__global__ void __launch_bounds__(256) k_attn_i2t(
    const u16* __restrict__ Qb, const u16* __restrict__ Kc,
    const u16* __restrict__ Vc, u16* __restrict__ out)
{
  __shared__ float Kl[32][132], Vl[32][132];
  int blk = blockIdx.x;
  int b = blk >> 7;
  int r0 = (blk & 127) * 32;
  for (int idx = threadIdx.x; idx < 4096; idx += 256) {
    int j = idx >> 7, c = idx & 127;
    Kl[j][c] = b2f(Kc[(size_t)(b * 32 + j) * 128 + c]);
    Vl[j][c] = b2f(Vc[(size_t)(b * 32 + j) * 128 + c]);
  }
  __syncthreads();
  int lr = threadIdx.x >> 3, h = threadIdx.x & 7;
  size_t row = (size_t)b * 4096 + r0 + lr;
  const u16* qp = Qb + row * 128 + h * 16;
  float q[16];
  {
    u16x8 qa = *(const u16x8*)qp;
    u16x8 qb2 = *(const u16x8*)(qp + 8);
#pragma unroll
    for (int e = 0; e < 8; ++e) { q[e] = b2f(qa[e]); q[8 + e] = b2f(qb2[e]); }
  }
  float lg[32];
  float mx = -INFINITY;
#pragma unroll
  for (int j = 0; j < 32; ++j) {
    float a = 0.f;
#pragma unroll
    for (int d = 0; d < 16; ++d) a += q[d] * Kl[j][h * 16 + d];
    lg[j] = a * 0.25f;
    mx = fmaxf(mx, lg[j]);
  }
  float sum = 0.f;
#pragma unroll
  for (int j = 0; j < 32; ++j) { lg[j] = __expf(lg[j] - mx); sum += lg[j]; }
  float acc[16];
#pragma unroll
  for (int d = 0; d < 16; ++d) acc[d] = 0.f;
#pragma unroll
  for (int j = 0; j < 32; ++j) {
    float p = lg[j];
#pragma unroll
    for (int d = 0; d < 16; ++d) acc[d] += p * Vl[j][h * 16 + d];
  }
  float inv = 1.f / sum;
  u16* op = out + row * 128 + h * 16;
#pragma unroll
  for (int d = 0; d < 16; ++d) op[d] = f2b(acc[d] * inv);
}

// ---------------------------------------------------------------------------
extern "C" void kernel_launch(void* const* d_in, const int* in_sizes, int n_in,
                              void* d_out, int out_size, void* d_ws, size_t ws_size,
                              hipStream_t stream)
{
  (void)in_sizes; (void)n_in; (void)out_size; (void)ws_size;
  const float* queries = (const float*)d_in[0];
  const float* keys    = (const float*)d_in[1];
  const float* qpe     = (const float*)d_in[2];
  const float* sa_qw = (const float*)d_in[3];  const float* sa_qb = (const float*)d_in[4];
  const float* sa_kw = (const float*)d_in[5];  const float* sa_kb = (const float*)d_in[6];
  const float* sa_vw = (const float*)d_in[7];  const float* sa_vb = (const float*)d_in[8];
  const float* sa_ow = (const float*)d_in[9];  const float* sa_ob = (const float*)d_in[10];
  const float* t2i_qw = (const float*)d_in[11]; const float* t2i_qb = (const float*)d_in[12];
  const float* t2i_kw = (const float*)d_in[13]; const float* t2i_kb = (const float*)d_in[14];
  const float* t2i_vw = (const float*)d_in[15]; const float* t2i_vb = (const float*)d_in[16];
  const float* t2i_ow = (const float*)d_in[17]; const float* t2i_ob = (const float*)d_in[18];
  const float* i2t_qw = (const float*)d_in[19]; const float* i2t_qb = (const float*)d_in[20];
  const float* i2t_kw = (const float*)d_in[21]; const float* i2t_kb = (const float*)d_in[22];
  const float* i2t_vw = (const float*)d_in[23]; const float* i2t_vb = (const float*)d_in[24];
  const float* i2t_ow = (const float*)d_in[25]; const float* i2t_ob = (const float*)d_in[26];
  const float* mlp_w1 = (const float*)d_in[27]; const float* mlp_b1 = (const float*)d_in[28];
  const float* mlp_w2 = (const float*)d_in[29]; const float* mlp_b2 = (const float*)d_in[30];
  const float* ln1_g = (const float*)d_in[31]; const float* ln1_b = (const float*)d_in[32];
  const float* ln2_g = (const float*)d_in[33]; const float* ln2_b = (const float*)d_in[34];
  const float* ln3_g = (const float*)d_in[35]; const float* ln3_b = (const float*)d_in[36];
  const float* ln4_g = (const float*)d_in[37]; const float* ln4_b = (const float*)d_in[38];

  float* out_q = (float*)d_out;            // [1024,256] f32
  float* out_k = out_q + 262144;           // [131072,256] f32 (128 MiB)

  u16* kvbuf  = (u16*)out_k;               // [131072][256] bf16 @ [0,64MiB)
  u16* qb_big = (u16*)out_k + 33554432;    // [131072][128] bf16 @ [64,96MiB)
  float* t2i_part = (float*)((u16*)out_k + 50331648);  // @ [96,~114MiB)

  char* ws = (char*)d_ws;
  size_t off = 0;
  auto alloc = [&](size_t bytes) -> char* {
    char* p = ws + off;
    off += (bytes + 255) & ~(size_t)255;
    return p;
  };
  u16* wt_saqkv = (u16*)alloc(768 * 256 * 2);
  u16* wt_saow  = (u16*)alloc(256 * 256 * 2);
  u16* wt_t2iq  = (u16*)alloc(128 * 256 * 2);
  u16* wt_kvq   = (u16*)alloc(384 * 256 * 2);   // t2i_k | t2i_v | i2t_q  ^T
  u16* wt_t2io  = (u16*)alloc(256 * 128 * 2);
  u16* wt_i2tk  = (u16*)alloc(128 * 256 * 2);
  u16* wt_i2tv  = (u16*)alloc(128 * 256 * 2);
  u16* wt_i2to  = (u16*)alloc(256 * 128 * 2);
  u16* wt_w1    = (u16*)alloc(2048 * 256 * 2);
  u16* wt_w2    = (u16*)alloc(256 * 2048 * 2);
  float* b_saqkv = (float*)alloc(768 * 4);
  float* b_kvq   = (float*)alloc(384 * 4);
  float* q1f = (float*)alloc(262144 * 4);
  u16* qt    = (u16*)alloc(131072 * 2);
  u16* at2   = (u16*)alloc(131072 * 2);
  u16* kc    = (u16*)alloc(131072 * 2);
  u16* vc    = (u16*)alloc(131072 * 2);
  u16* ab_big = (u16*)alloc((size_t)16777216 * 2);  // [131072][128] bf16, 32MB

  // --- 1. weight prep ---
  TArgs ta{};
  int nb = 0, id = 0;
  auto addT = [&](const float* s, void* d, int K, int N, int mode) {
    ta.d[id].src = s; ta.d[id].dst = d; ta.d[id].K = K; ta.d[id].N = N;
    ta.d[id].mode = mode; ta.d[id].blk0 = nb;
    nb += (K * N + 255) / 256;
    ++id;
  };
  addT(sa_qw, wt_saqkv, 256, 256, 0);
  addT(sa_kw, wt_saqkv + 256 * 256, 256, 256, 0);
  addT(sa_vw, wt_saqkv + 512 * 256, 256, 256, 0);
  addT(sa_ow, wt_saow, 256, 256, 0);
  addT(t2i_qw, wt_t2iq, 256, 128, 0);
  addT(t2i_kw, wt_kvq, 256, 128, 0);
  addT(t2i_vw, wt_kvq + 128 * 256, 256, 128, 0);
  addT(i2t_qw, wt_kvq + 256 * 256, 256, 128, 0);
  addT(t2i_ow, wt_t2io, 128, 256, 0);
  addT(i2t_kw, wt_i2tk, 256, 128, 0);
  addT(i2t_vw, wt_i2tv, 256, 128, 0);
  addT(i2t_ow, wt_i2to, 128, 256, 0);
  addT(mlp_w1, wt_w1, 256, 2048, 0);
  addT(mlp_w2, wt_w2, 2048, 256, 0);
  addT(sa_qb, b_saqkv, 1, 256, 1);
  addT(sa_kb, b_saqkv + 256, 1, 256, 1);
  addT(sa_vb, b_saqkv + 512, 1, 256, 1);
  addT(t2i_kb, b_kvq, 1, 128, 1);
  addT(t2i_vb, b_kvq + 128, 1, 128, 1);
  addT(i2t_qb, b_kvq + 256, 1, 128, 1);
  ta.n = id;
  k_trans<<<nb, 256, 0, stream>>>(ta);

  // --- 2. queries phase 1 (fused) ---
  k_qphase1<<<32, 256, 0, stream>>>(queries, qpe, wt_saqkv, b_saqkv,
                                    wt_saow, sa_ob, ln1_g, ln1_b,
                                    wt_t2iq, t2i_qb, q1f, qt);
  // --- 3. fused keys projections ---
  k_gemm_kvq<<<1024, 512, 0, stream>>>(keys, wt_kvq, b_kvq, kvbuf, qb_big);
  // --- 4. t2i attention: split-K partials + merge ---
  k_attn_t2i_part<<<dim3(32, 32), 128, 0, stream>>>(qt, kvbuf, t2i_part);
  k_attn_t2i_merge<<<256, 256, 0, stream>>>(t2i_part, at2);
  // --- 5. queries phase 2 (fused): t2i-out+ln2+MLP+ln3 -> out_q, kc, vc ---
  k_qphase2<<<32, 256, 0, stream>>>(at2, q1f, wt_t2io, t2i_ob, ln2_g, ln2_b,
                                    wt_w1, mlp_b1, wt_w2, mlp_b2,
                                    ln3_g, ln3_b, qpe,
                                    wt_i2tk, i2t_kb, wt_i2tv, i2t_vb,
                                    out_q, kc, vc);
  // --- 6. i2t attention: qb_big -> ab_big (ws) ---
  k_attn_i2t<<<4096, 256, 0, stream>>>(qb_big, kc, vc, ab_big);
  // --- 7. i2t out proj + keys residual + ln4 -> f32 out_k ---
  k_gemm_ln<<<2048, 256, 0, stream>>>(ab_big, wt_i2to, i2t_ob, keys,
                                      ln4_g, ln4_b, out_k);
}